// Round 13
// baseline (60.004 us; speedup 1.0000x reference)
//
#include <hip/hip_runtime.h>
#include <stdint.h>

#define BATCH 16
#define NPTS  4096
#define TOT   (BATCH * NPTS)     // 65536 points per tensor
#define TWOTOT (2 * TOT)

typedef float f4 __attribute__((ext_vector_type(4)));
typedef uint32_t u32;

// ---- scalar fp32 math, all-VGPR operands, interleaved chains ----
#define FMA1(d, pz, q) \
    asm("v_fma_f32 %0, %1, %2, %3" : "=v"(d) : "v"(pz), "v"(q.z), "v"(q.w))
#define FMACY(d, py, q) \
    asm("v_fmac_f32 %0, %1, %2" : "+v"(d) : "v"(py), "v"(q.y))
#define FMACX(d, px, q) \
    asm("v_fmac_f32 %0, %1, %2" : "+v"(d) : "v"(px), "v"(q.x))
#define MIN3(acc, u, v) \
    asm("v_min3_f32 %0, %1, %2, %0" : "+v"(acc) : "v"(u), "v"(v))

#define S1A(i, qA, qB) FMA1(dA##i, nz##i, qA); FMA1(dB##i, nz##i, qB);
#define S2A(i, qA, qB) FMACY(dA##i, ny##i, qA); FMACY(dB##i, ny##i, qB);
#define S3A(i, qA, qB) FMACX(dA##i, nx##i, qA); FMACX(dB##i, nx##i, qB);
#define SMN(i, qA, qB) MIN3(acc##i, dA##i, dB##i);

#define REP16(M, qA, qB) \
    M(0,qA,qB)  M(1,qA,qB)  M(2,qA,qB)  M(3,qA,qB)  \
    M(4,qA,qB)  M(5,qA,qB)  M(6,qA,qB)  M(7,qA,qB)  \
    M(8,qA,qB)  M(9,qA,qB)  M(10,qA,qB) M(11,qA,qB) \
    M(12,qA,qB) M(13,qA,qB) M(14,qA,qB) M(15,qA,qB)

// 2 Q points (VGPR-broadcast) vs the thread's 16 P points.
// Emission: 32x step1, 32x step2, 32x step3, 16x min3 -> dependent ops are
// 32 instrs (64 cy) apart: zero hazard bubbles. 112 instrs per 32 pair-evals.
#define COMP2V(qA, qB)                                                      \
    do {                                                                    \
        float dA0, dA1, dA2, dA3, dA4, dA5, dA6, dA7;                       \
        float dA8, dA9, dA10, dA11, dA12, dA13, dA14, dA15;                 \
        float dB0, dB1, dB2, dB3, dB4, dB5, dB6, dB7;                       \
        float dB8, dB9, dB10, dB11, dB12, dB13, dB14, dB15;                 \
        REP16(S1A, qA, qB)                                                  \
        REP16(S2A, qA, qB)                                                  \
        REP16(S3A, qA, qB)                                                  \
        REP16(SMN, qA, qB)                                                  \
    } while (0)

// uniform-address LDS broadcast read of one Q point (16B). LDS completes
// IN ORDER -> counted lgkmcnt waits are safe (unlike SMEM).
#define DSR(dst, imm) \
    asm volatile("ds_read_b128 %0, %1 offset:" imm : "=v"(dst) : "v"(lofs))

// counted wait: only the oldest 2 of 16 outstanding ds_reads; ties the two
// slots so dependent math can't hoist; sched_barrier fences (rule #18).
#define WAITL(cnt, qa, qb)                                      \
    do {                                                        \
        asm volatile("s_waitcnt lgkmcnt(" cnt ")"               \
                     : "+v"(qa), "+v"(qb));                     \
        __builtin_amdgcn_sched_barrier(0);                      \
    } while (0)

#define STEPV(qa, qb, immA, immB)                               \
    do {                                                        \
        WAITL("14", qa, qb);                                    \
        COMP2V(qa, qb);                                         \
        DSR(qa, immA); DSR(qb, immB);                           \
    } while (0)

#define STEPD(cnt, qa, qb)  do { WAITL(cnt, qa, qb); COMP2V(qa, qb); } while (0)

// Pack {x, y, z, |q|^2} AoS float4 per point; also zero the output scalar.
// pk layout: [2][BATCH][NPTS] f4 ; slot 0 = x tensor, slot 1 = y tensor.
__global__ __launch_bounds__(256) void pack_kernel(const float* __restrict__ x,
                                                   const float* __restrict__ y,
                                                   f4* __restrict__ pk,
                                                   float* __restrict__ out) {
    int idx = blockIdx.x * 256 + threadIdx.x;       // 0 .. 2*TOT-1
    if (idx == 0) out[0] = 0.0f;
    const float* src = (idx < TOT) ? x : y;
    int r = (idx < TOT) ? idx : (idx - TOT);
    float a = src[r * 3 + 0];
    float b = src[r * 3 + 1];
    float c = src[r * 3 + 2];
    f4 v = {a, b, c, fmaf(a, a, fmaf(b, b, c * c))};
    pk[idx] = v;
}

// Pass 1: each thread owns SIXTEEN consecutive P points (one (dir,batch) row
// per block). Q segment staged once to LDS; streamed via uniform ds_read_b128
// broadcast through a 16-slot rotating pipeline with counted lgkmcnt(14)
// waits. One 16B LDS read now feeds 32 pair-evals (2x R12) -> LDS pipe at
// ~43% of the VALU window, queue-free.
template <int QSEGT>
__global__ __launch_bounds__(256) void chamfer_pass1(const f4* __restrict__ pk,
                                                     float* __restrict__ part) {
    constexpr int QLENT = NPTS / QSEGT;
    constexpr int NGRP  = QLENT / 16;         // 16-Q groups per segment

    __shared__ f4 qlds[QLENT];

    int qseg  = blockIdx.x & (QSEGT - 1);
    int chunk = blockIdx.x / QSEGT;           // 0..31 = dir*16 + batch

    int dir   = chunk >> 4;
    int bb    = chunk & 15;

    // stage Q segment into LDS (once)
    const f4* __restrict__ qsrc = pk + (1 - dir) * TOT + bb * NPTS + qseg * QLENT;
    for (int i = threadIdx.x; i < QLENT; i += 256) qlds[i] = qsrc[i];

    int pidx0 = chunk * NPTS + threadIdx.x * 16;
    f4 p0  = pk[pidx0 + 0],  p1  = pk[pidx0 + 1],  p2  = pk[pidx0 + 2],  p3  = pk[pidx0 + 3];
    f4 p4  = pk[pidx0 + 4],  p5  = pk[pidx0 + 5],  p6  = pk[pidx0 + 6],  p7  = pk[pidx0 + 7];
    f4 p8  = pk[pidx0 + 8],  p9  = pk[pidx0 + 9],  p10 = pk[pidx0 + 10], p11 = pk[pidx0 + 11];
    f4 p12 = pk[pidx0 + 12], p13 = pk[pidx0 + 13], p14 = pk[pidx0 + 14], p15 = pk[pidx0 + 15];
    float nx0  = -2.0f * p0.x,  ny0  = -2.0f * p0.y,  nz0  = -2.0f * p0.z;
    float nx1  = -2.0f * p1.x,  ny1  = -2.0f * p1.y,  nz1  = -2.0f * p1.z;
    float nx2  = -2.0f * p2.x,  ny2  = -2.0f * p2.y,  nz2  = -2.0f * p2.z;
    float nx3  = -2.0f * p3.x,  ny3  = -2.0f * p3.y,  nz3  = -2.0f * p3.z;
    float nx4  = -2.0f * p4.x,  ny4  = -2.0f * p4.y,  nz4  = -2.0f * p4.z;
    float nx5  = -2.0f * p5.x,  ny5  = -2.0f * p5.y,  nz5  = -2.0f * p5.z;
    float nx6  = -2.0f * p6.x,  ny6  = -2.0f * p6.y,  nz6  = -2.0f * p6.z;
    float nx7  = -2.0f * p7.x,  ny7  = -2.0f * p7.y,  nz7  = -2.0f * p7.z;
    float nx8  = -2.0f * p8.x,  ny8  = -2.0f * p8.y,  nz8  = -2.0f * p8.z;
    float nx9  = -2.0f * p9.x,  ny9  = -2.0f * p9.y,  nz9  = -2.0f * p9.z;
    float nx10 = -2.0f * p10.x, ny10 = -2.0f * p10.y, nz10 = -2.0f * p10.z;
    float nx11 = -2.0f * p11.x, ny11 = -2.0f * p11.y, nz11 = -2.0f * p11.z;
    float nx12 = -2.0f * p12.x, ny12 = -2.0f * p12.y, nz12 = -2.0f * p12.z;
    float nx13 = -2.0f * p13.x, ny13 = -2.0f * p13.y, nz13 = -2.0f * p13.z;
    float nx14 = -2.0f * p14.x, ny14 = -2.0f * p14.y, nz14 = -2.0f * p14.z;
    float nx15 = -2.0f * p15.x, ny15 = -2.0f * p15.y, nz15 = -2.0f * p15.z;
    asm volatile("" :: "v"(nx0), "v"(nx1), "v"(nx2), "v"(nx3), "v"(nx4), "v"(nx5),
                       "v"(nx6), "v"(nx7), "v"(nx8), "v"(nx9), "v"(nx10), "v"(nx11),
                       "v"(nx12), "v"(nx13), "v"(nx14), "v"(nx15));
    asm volatile("" :: "v"(ny0), "v"(ny1), "v"(ny2), "v"(ny3), "v"(ny4), "v"(ny5),
                       "v"(ny6), "v"(ny7), "v"(ny8), "v"(ny9), "v"(ny10), "v"(ny11),
                       "v"(ny12), "v"(ny13), "v"(ny14), "v"(ny15));
    asm volatile("" :: "v"(nz0), "v"(nz1), "v"(nz2), "v"(nz3), "v"(nz4), "v"(nz5),
                       "v"(nz6), "v"(nz7), "v"(nz8), "v"(nz9), "v"(nz10), "v"(nz11),
                       "v"(nz12), "v"(nz13), "v"(nz14), "v"(nz15));
    __builtin_amdgcn_sched_barrier(0);

    __syncthreads();   // staging complete

    float acc0  = 3.4e38f, acc1  = 3.4e38f, acc2  = 3.4e38f, acc3  = 3.4e38f;
    float acc4  = 3.4e38f, acc5  = 3.4e38f, acc6  = 3.4e38f, acc7  = 3.4e38f;
    float acc8  = 3.4e38f, acc9  = 3.4e38f, acc10 = 3.4e38f, acc11 = 3.4e38f;
    float acc12 = 3.4e38f, acc13 = 3.4e38f, acc14 = 3.4e38f, acc15 = 3.4e38f;

    u32 lofs = (u32)(uintptr_t)&qlds[0];

    f4 s0, s1, s2, s3, s4, s5, s6, s7, s8, s9, s10, s11, s12, s13, s14, s15;
    DSR(s0, "0");    DSR(s1, "16");   DSR(s2, "32");   DSR(s3, "48");
    DSR(s4, "64");   DSR(s5, "80");   DSR(s6, "96");   DSR(s7, "112");
    DSR(s8, "128");  DSR(s9, "144");  DSR(s10, "160"); DSR(s11, "176");
    DSR(s12, "192"); DSR(s13, "208"); DSR(s14, "224"); DSR(s15, "240");
    lofs += 256;

    #pragma unroll 1
    for (int g = 0; g < NGRP - 1; ++g) {
        STEPV(s0,  s1,  "0",   "16");
        STEPV(s2,  s3,  "32",  "48");
        STEPV(s4,  s5,  "64",  "80");
        STEPV(s6,  s7,  "96",  "112");
        STEPV(s8,  s9,  "128", "144");
        STEPV(s10, s11, "160", "176");
        STEPV(s12, s13, "192", "208");
        STEPV(s14, s15, "224", "240");
        lofs += 256;
    }
    STEPD("14", s0,  s1);
    STEPD("12", s2,  s3);
    STEPD("10", s4,  s5);
    STEPD("8",  s6,  s7);
    STEPD("6",  s8,  s9);
    STEPD("4",  s10, s11);
    STEPD("2",  s12, s13);
    STEPD("0",  s14, s15);

    f4 r0 = {acc0,  acc1,  acc2,  acc3};
    f4 r1 = {acc4,  acc5,  acc6,  acc7};
    f4 r2 = {acc8,  acc9,  acc10, acc11};
    f4 r3 = {acc12, acc13, acc14, acc15};
    f4* dst = (f4*)(part + qseg * TWOTOT + pidx0);
    dst[0] = r0; dst[1] = r1; dst[2] = r2; dst[3] = r3;
}

// Pass 2: 4 points per thread, f4 loads of the partials, add |p|^2,
// block-reduce, one atomic per block.
__global__ __launch_bounds__(256) void chamfer_pass2(const f4* __restrict__ part4,
                                                     const float* __restrict__ pkf,
                                                     float* __restrict__ out,
                                                     int nseg) {
    int t4  = blockIdx.x * 256 + threadIdx.x;     // 0..TWOTOT/4-1
    f4 m = part4[t4];
    for (int s = 1; s < nseg; ++s) {
        f4 v = part4[s * (TWOTOT / 4) + t4];
        m.x = fminf(m.x, v.x); m.y = fminf(m.y, v.y);
        m.z = fminf(m.z, v.z); m.w = fminf(m.w, v.w);
    }
    int gid = t4 * 4;
    float r = (m.x + pkf[(gid + 0) * 4 + 3]) + (m.y + pkf[(gid + 1) * 4 + 3])
            + (m.z + pkf[(gid + 2) * 4 + 3]) + (m.w + pkf[(gid + 3) * 4 + 3]);

    float s = r;
    #pragma unroll
    for (int off = 32; off; off >>= 1) s += __shfl_down(s, off);
    __shared__ float red[4];
    int lane = threadIdx.x & 63, wid = threadIdx.x >> 6;
    if (lane == 0) red[wid] = s;
    __syncthreads();
    if (threadIdx.x == 0) {
        float tot = (red[0] + red[1]) + (red[2] + red[3]);
        atomicAdd(out, tot * (1.0f / (float)TOT));
    }
}

// ---------------- fallback (no workspace): direct form ----------------
__global__ __launch_bounds__(256) void chamfer_direct(const float* __restrict__ x,
                                                      const float* __restrict__ y,
                                                      float* __restrict__ out) {
    int blk   = blockIdx.x;
    int dir   = blk >> 8;
    int t     = blk & 255;
    int b     = t >> 4;
    int chunk = t & 15;

    const float* __restrict__ P = (dir ? y : x) + (b * NPTS + chunk * 256) * 3;
    const float* __restrict__ Q = (dir ? x : y) + b * NPTS * 3;

    float px = P[threadIdx.x * 3 + 0];
    float py = P[threadIdx.x * 3 + 1];
    float pz = P[threadIdx.x * 3 + 2];

    float b0 = 3.4e38f, b1 = 3.4e38f, b2 = 3.4e38f, b3 = 3.4e38f;
    for (int j = 0; j < NPTS; j += 4) {
        #pragma unroll
        for (int u = 0; u < 4; ++u) {
            float dx = px - Q[(j + u) * 3 + 0];
            float dy = py - Q[(j + u) * 3 + 1];
            float dz = pz - Q[(j + u) * 3 + 2];
            float d  = fmaf(dx, dx, fmaf(dy, dy, dz * dz));
            if (u == 0) b0 = fminf(b0, d);
            if (u == 1) b1 = fminf(b1, d);
            if (u == 2) b2 = fminf(b2, d);
            if (u == 3) b3 = fminf(b3, d);
        }
    }
    float best = fminf(fminf(b0, b1), fminf(b2, b3));

    float v = best;
    #pragma unroll
    for (int off = 32; off; off >>= 1) v += __shfl_down(v, off);
    __shared__ float red[4];
    int lane = threadIdx.x & 63, wid = threadIdx.x >> 6;
    if (lane == 0) red[wid] = v;
    __syncthreads();
    if (threadIdx.x == 0) {
        float s = (red[0] + red[1]) + (red[2] + red[3]);
        atomicAdd(out, s * (1.0f / (float)TOT));
    }
}

__global__ void zero_kernel(float* out) { out[0] = 0.0f; }

extern "C" void kernel_launch(void* const* d_in, const int* in_sizes, int n_in,
                              void* d_out, int out_size, void* d_ws, size_t ws_size,
                              hipStream_t stream) {
    const float* x = (const float*)d_in[0];
    const float* y = (const float*)d_in[1];
    float* out = (float*)d_out;

    size_t pk_bytes = (size_t)TWOTOT * 4 * sizeof(float);         // 2 MiB
    auto part_bytes = [&](int qseg) { return (size_t)qseg * TWOTOT * sizeof(float); };

    if (ws_size >= pk_bytes + part_bytes(16)) {
        // QSEG = 16 : grid 512 (2 blocks/CU), part 8 MiB, LDS 4KB/block
        float* pkf  = (float*)d_ws;
        float* part = (float*)((char*)d_ws + pk_bytes);
        hipLaunchKernelGGL(pack_kernel, dim3(TWOTOT / 256), dim3(256), 0, stream,
                           x, y, (f4*)pkf, out);
        hipLaunchKernelGGL((chamfer_pass1<16>), dim3(32 * 16), dim3(256), 0, stream,
                           (const f4*)pkf, part);
        hipLaunchKernelGGL(chamfer_pass2, dim3(TWOTOT / 4 / 256), dim3(256), 0, stream,
                           (const f4*)part, pkf, out, 16);
    } else if (ws_size >= pk_bytes + part_bytes(8)) {
        // QSEG = 8 : grid 256, part 4 MiB, LDS 8KB/block
        float* pkf  = (float*)d_ws;
        float* part = (float*)((char*)d_ws + pk_bytes);
        hipLaunchKernelGGL(pack_kernel, dim3(TWOTOT / 256), dim3(256), 0, stream,
                           x, y, (f4*)pkf, out);
        hipLaunchKernelGGL((chamfer_pass1<8>), dim3(32 * 8), dim3(256), 0, stream,
                           (const f4*)pkf, part);
        hipLaunchKernelGGL(chamfer_pass2, dim3(TWOTOT / 4 / 256), dim3(256), 0, stream,
                           (const f4*)part, pkf, out, 8);
    } else if (ws_size >= pk_bytes + part_bytes(4)) {
        // QSEG = 4 : grid 128, part 2 MiB, LDS 16KB/block
        float* pkf  = (float*)d_ws;
        float* part = (float*)((char*)d_ws + pk_bytes);
        hipLaunchKernelGGL(pack_kernel, dim3(TWOTOT / 256), dim3(256), 0, stream,
                           x, y, (f4*)pkf, out);
        hipLaunchKernelGGL((chamfer_pass1<4>), dim3(32 * 4), dim3(256), 0, stream,
                           (const f4*)pkf, part);
        hipLaunchKernelGGL(chamfer_pass2, dim3(TWOTOT / 4 / 256), dim3(256), 0, stream,
                           (const f4*)part, pkf, out, 4);
    } else {
        hipLaunchKernelGGL(zero_kernel, dim3(1), dim3(1), 0, stream, out);
        hipLaunchKernelGGL(chamfer_direct, dim3(512), dim3(256), 0, stream, x, y, out);
    }
}

// Round 14
// 57.012 us; speedup vs baseline: 1.0525x; 1.0525x over previous
//
#include <hip/hip_runtime.h>
#include <stdint.h>

#define BATCH 16
#define NPTS  4096
#define TOT   (BATCH * NPTS)     // 65536 points per tensor
#define TWOTOT (2 * TOT)

typedef float f4 __attribute__((ext_vector_type(4)));
typedef float f32x4 __attribute__((ext_vector_type(4)));
typedef short bh8 __attribute__((ext_vector_type(8)));   // 8 bf16 = 4 VGPR
typedef uint32_t u32;
typedef unsigned short u16;
typedef unsigned long long u64;

__device__ __forceinline__ u16 bfr(float f) {
    union { float f; u32 u; } v; v.f = f;
    u32 r = v.u + 0x7FFF + ((v.u >> 16) & 1);
    return (u16)(r >> 16);
}
__device__ __forceinline__ float bfback(u16 h) {
    union { u32 u; float f; } v; v.u = ((u32)h) << 16; return v.f;
}
#define BF16_ONE ((u16)0x3F80)

#define MIN3r(d, a, b, c) \
    asm("v_min3_f32 %0, %1, %2, %3" : "=v"(d) : "v"(a), "v"(b), "v"(c))

// pack: A-record per x-point, B-record per y-point (16 bf16 = 32B each).
//  A: [ahx,ahy,ahz, ahx,ahy,ahz, alx,aly, alz, x2h,x2l, 1,1, 0,0,0]   (A=-2x)
//  B: [yhx,yhy,yhz, ylx,yly,ylz, yhx,yhy, yhz, 1,1, y2h,y2l, 0,0,0]
// => sum_k A_k*B_k = Ah.Yh + Ah.Yl + Al.Yh + x2 + y2 == D[i,j]  (al.yl dropped)
__global__ __launch_bounds__(256) void pack_mfma(const float* __restrict__ x,
                                                 const float* __restrict__ y,
                                                 u16* __restrict__ Arec,
                                                 u16* __restrict__ Brec,
                                                 float* __restrict__ zeros16,
                                                 float* __restrict__ out) {
    int idx = blockIdx.x * 256 + threadIdx.x;        // 0..2*TOT-1
    if (idx == 0) out[0] = 0.0f;
    if (idx == 1) { f4 z = {0.f, 0.f, 0.f, 0.f}; *(f4*)zeros16 = z; }

    bool isx = idx < TOT;
    int r = isx ? idx : (idx - TOT);
    const float* src = isx ? x : y;
    float a = src[r * 3 + 0];
    float b = src[r * 3 + 1];
    float c = src[r * 3 + 2];
    float s2 = fmaf(a, a, fmaf(b, b, c * c));
    u16 s2h = bfr(s2);
    u16 s2l = bfr(s2 - bfback(s2h));

    union { u16 h[16]; f4 v[2]; } rec;
    if (isx) {
        float ax = -2.0f * a, ay = -2.0f * b, az = -2.0f * c;
        u16 ahx = bfr(ax), ahy = bfr(ay), ahz = bfr(az);
        u16 alx = bfr(ax - bfback(ahx));
        u16 aly = bfr(ay - bfback(ahy));
        u16 alz = bfr(az - bfback(ahz));
        rec.h[0] = ahx;  rec.h[1] = ahy;  rec.h[2] = ahz;
        rec.h[3] = ahx;  rec.h[4] = ahy;  rec.h[5] = ahz;
        rec.h[6] = alx;  rec.h[7] = aly;
        rec.h[8] = alz;  rec.h[9] = s2h;  rec.h[10] = s2l;
        rec.h[11] = BF16_ONE; rec.h[12] = BF16_ONE;
        rec.h[13] = 0; rec.h[14] = 0; rec.h[15] = 0;
        f4* dst = (f4*)(Arec + (size_t)r * 16);
        dst[0] = rec.v[0]; dst[1] = rec.v[1];
    } else {
        u16 yhx = bfr(a), yhy = bfr(b), yhz = bfr(c);
        u16 ylx = bfr(a - bfback(yhx));
        u16 yly = bfr(b - bfback(yhy));
        u16 ylz = bfr(c - bfback(yhz));
        rec.h[0] = yhx;  rec.h[1] = yhy;  rec.h[2] = yhz;
        rec.h[3] = ylx;  rec.h[4] = yly;  rec.h[5] = ylz;
        rec.h[6] = yhx;  rec.h[7] = yhy;
        rec.h[8] = yhz;  rec.h[9] = BF16_ONE; rec.h[10] = BF16_ONE;
        rec.h[11] = s2h; rec.h[12] = s2l;
        rec.h[13] = 0; rec.h[14] = 0; rec.h[15] = 0;
        f4* dst = (f4*)(Brec + (size_t)r * 16);
        dst[0] = rec.v[0]; dst[1] = rec.v[1];
    }
}

#define GLOADB(B) do { \
    asm volatile("global_load_dwordx4 %0, %1, off" : "=v"(B) : "v"(baddr)); \
    baddr += bstep; \
} while (0)

#define WAITV(cnt, B) do { \
    asm volatile("s_waitcnt vmcnt(" cnt ")" : "+v"(B)); \
    __builtin_amdgcn_sched_barrier(0); \
} while (0)

#define MF4(P, BB) do { \
    P##0 = __builtin_amdgcn_mfma_f32_16x16x32_bf16(af0, BB, zc, 0, 0, 0); \
    P##1 = __builtin_amdgcn_mfma_f32_16x16x32_bf16(af1, BB, zc, 0, 0, 0); \
    P##2 = __builtin_amdgcn_mfma_f32_16x16x32_bf16(af2, BB, zc, 0, 0, 0); \
    P##3 = __builtin_amdgcn_mfma_f32_16x16x32_bf16(af3, BB, zc, 0, 0, 0); \
} while (0)

// Epilogue for one j-tile: rowmins fold per lane position (C layout:
// col=lane&15, row=(lane>>4)*4+reg) + column min over the lane's 16 values
// (all share col=lane&15) -> fire-and-forget ds_min_f32 (4 lanes per col
// reduce in the LDS atomic unit, no cross-lane shuffles in the loop).
#define EPI(P) do { \
    r00=fminf(r00,P##0[0]); r01=fminf(r01,P##0[1]); r02=fminf(r02,P##0[2]); r03=fminf(r03,P##0[3]); \
    r10=fminf(r10,P##1[0]); r11=fminf(r11,P##1[1]); r12=fminf(r12,P##1[2]); r13=fminf(r13,P##1[3]); \
    r20=fminf(r20,P##2[0]); r21=fminf(r21,P##2[1]); r22=fminf(r22,P##2[2]); r23=fminf(r23,P##2[3]); \
    r30=fminf(r30,P##3[0]); r31=fminf(r31,P##3[1]); r32=fminf(r32,P##3[2]); r33=fminf(r33,P##3[3]); \
    float t0,t1,t2,t3,t4,t5,t6,cv; \
    MIN3r(t0, P##0[0], P##0[1], P##0[2]); \
    MIN3r(t1, P##0[3], P##1[0], P##1[1]); \
    MIN3r(t2, P##1[2], P##1[3], P##2[0]); \
    MIN3r(t3, P##2[1], P##2[2], P##2[3]); \
    MIN3r(t4, P##3[0], P##3[1], P##3[2]); \
    t5 = fminf(P##3[3], t0); \
    MIN3r(t6, t1, t2, t3); \
    MIN3r(cv, t4, t5, t6); \
    asm volatile("ds_min_f32 %0, %1" :: "v"(cma), "v"(cv)); \
    cma += 64; \
} while (0)

// Block = (batch, 256-row i-chunk); 4 waves x 64 rows, A-stationary;
// streams all 256 j-tiles with a 4-slot rotating B prefetch. Both direction
// mins come from ONE distance evaluation (halves total pair count).
__global__ __launch_bounds__(256) void chamfer_mfma(const u16* __restrict__ Arec,
                                                    const u16* __restrict__ Brec,
                                                    const float* __restrict__ zeros16,
                                                    float* __restrict__ colpart,
                                                    float* __restrict__ out) {
    __shared__ float colmin[NPTS];
    int b    = blockIdx.x >> 4;
    int ic   = blockIdx.x & 15;
    int tid  = threadIdx.x;
    int wv   = tid >> 6, lane = tid & 63;
    int lg   = lane >> 4, lm = lane & 15;

    for (int i = tid; i < NPTS; i += 256) colmin[i] = 3.4e38f;

    int i0 = ic * 256 + wv * 64;

    // A frags: lane holds row lane&15, K-chunk (lane>>4)*8..+7; records are
    // 16 bf16 so only lg<2 carries data (K>=16 is structurally zero).
    bh8 af0, af1, af2, af3;
    {
        bh8 z8 = {0, 0, 0, 0, 0, 0, 0, 0};
        const u16* ab = Arec + ((size_t)b * NPTS + i0 + lm) * 16 + lg * 8;
        af0 = (lg < 2) ? *(const bh8*)(ab + 0)   : z8;
        af1 = (lg < 2) ? *(const bh8*)(ab + 256) : z8;
        af2 = (lg < 2) ? *(const bh8*)(ab + 512) : z8;
        af3 = (lg < 2) ? *(const bh8*)(ab + 768) : z8;
    }
    asm volatile("s_waitcnt vmcnt(0)" ::: "memory");
    __syncthreads();

    u64 baddr, bstep;
    {
        u64 real = (u64)(uintptr_t)(Brec + ((size_t)b * NPTS + lm) * 16 + lg * 8);
        u64 zadr = (u64)(uintptr_t)zeros16;
        baddr = (lg < 2) ? real : zadr;
        bstep = (lg < 2) ? (u64)512 : (u64)0;   // 16 points * 32B per tile
    }
    u32 cma = (u32)(uintptr_t)&colmin[0] + (u32)lm * 4;

    f32x4 zc = {0.f, 0.f, 0.f, 0.f};
    float r00=3.4e38f, r01=3.4e38f, r02=3.4e38f, r03=3.4e38f;
    float r10=3.4e38f, r11=3.4e38f, r12=3.4e38f, r13=3.4e38f;
    float r20=3.4e38f, r21=3.4e38f, r22=3.4e38f, r23=3.4e38f;
    float r30=3.4e38f, r31=3.4e38f, r32=3.4e38f, r33=3.4e38f;

    f32x4 aA0, aA1, aA2, aA3, aB0, aB1, aB2, aB3;
    bh8 b0, b1, b2, b3;

    GLOADB(b0); GLOADB(b1); GLOADB(b2); GLOADB(b3);   // tiles 0..3
    WAITV("3", b0);
    MF4(aA, b0);                                       // tile 0
    GLOADB(b0);                                        // tile 4

    #pragma unroll 1
    for (int k = 0; k < 63; ++k) {
        WAITV("3", b1); MF4(aB, b1); GLOADB(b1); EPI(aA);
        WAITV("3", b2); MF4(aA, b2); GLOADB(b2); EPI(aB);
        WAITV("3", b3); MF4(aB, b3); GLOADB(b3); EPI(aA);
        WAITV("3", b0); MF4(aA, b0); GLOADB(b0); EPI(aB);
    }
    WAITV("3", b1); MF4(aB, b1); EPI(aA);             // tile 253 / epi 252
    WAITV("2", b2); MF4(aA, b2); EPI(aB);             // 254 / 253
    WAITV("1", b3); MF4(aB, b3); EPI(aA);             // 255 / 254
    WAITV("0", b0); EPI(aB);                          // (256=garbage) / 255

    #define RRED(r) { r = fminf(r, __shfl_xor(r, 1)); r = fminf(r, __shfl_xor(r, 2)); \
                      r = fminf(r, __shfl_xor(r, 4)); r = fminf(r, __shfl_xor(r, 8)); }
    RRED(r00) RRED(r01) RRED(r02) RRED(r03)
    RRED(r10) RRED(r11) RRED(r12) RRED(r13)
    RRED(r20) RRED(r21) RRED(r22) RRED(r23)
    RRED(r30) RRED(r31) RRED(r32) RRED(r33)
    float ps = (((r00 + r01) + (r02 + r03)) + ((r10 + r11) + (r12 + r13)))
             + (((r20 + r21) + (r22 + r23)) + ((r30 + r31) + (r32 + r33)));
    ps *= (1.0f / 16.0f);                  // each row replicated across 16 lanes
    #pragma unroll
    for (int off = 32; off; off >>= 1) ps += __shfl_down(ps, off);
    if (lane == 0) atomicAdd(out, ps * (1.0f / (float)TOT));

    __syncthreads();                       // all ds_min retired
    for (int j = tid; j < NPTS; j += 256)
        colpart[(size_t)ic * TOT + b * NPTS + j] = colmin[j];
}

// pass2: combine 16 per-i-chunk column-min partials, mean, accumulate.
__global__ __launch_bounds__(256) void colmin_pass2(const float* __restrict__ colpart,
                                                    float* __restrict__ out) {
    int t = blockIdx.x * 256 + threadIdx.x;           // (b,j) flattened
    float m = colpart[t];
    #pragma unroll
    for (int ic = 1; ic < 16; ++ic) m = fminf(m, colpart[(size_t)ic * TOT + t]);

    float s = m;
    #pragma unroll
    for (int off = 32; off; off >>= 1) s += __shfl_down(s, off);
    __shared__ float red[4];
    int lane = threadIdx.x & 63, wid = threadIdx.x >> 6;
    if (lane == 0) red[wid] = s;
    __syncthreads();
    if (threadIdx.x == 0) {
        float tot = (red[0] + red[1]) + (red[2] + red[3]);
        atomicAdd(out, tot * (1.0f / (float)TOT));
    }
}

// ---------------- fallback (no workspace): direct form ----------------
__global__ __launch_bounds__(256) void chamfer_direct(const float* __restrict__ x,
                                                      const float* __restrict__ y,
                                                      float* __restrict__ out) {
    int blk = blockIdx.x;
    int dir = blk >> 8;
    int t = blk & 255;
    int b = t >> 4;
    int chunk = t & 15;
    const float* __restrict__ P = (dir ? y : x) + (b * NPTS + chunk * 256) * 3;
    const float* __restrict__ Q = (dir ? x : y) + b * NPTS * 3;
    float px = P[threadIdx.x * 3 + 0];
    float py = P[threadIdx.x * 3 + 1];
    float pz = P[threadIdx.x * 3 + 2];
    float b0 = 3.4e38f, b1 = 3.4e38f, b2 = 3.4e38f, b3 = 3.4e38f;
    for (int j = 0; j < NPTS; j += 4) {
        #pragma unroll
        for (int u = 0; u < 4; ++u) {
            float dx = px - Q[(j + u) * 3 + 0];
            float dy = py - Q[(j + u) * 3 + 1];
            float dz = pz - Q[(j + u) * 3 + 2];
            float d = fmaf(dx, dx, fmaf(dy, dy, dz * dz));
            if (u == 0) b0 = fminf(b0, d);
            if (u == 1) b1 = fminf(b1, d);
            if (u == 2) b2 = fminf(b2, d);
            if (u == 3) b3 = fminf(b3, d);
        }
    }
    float best = fminf(fminf(b0, b1), fminf(b2, b3));
    float v = best;
    #pragma unroll
    for (int off = 32; off; off >>= 1) v += __shfl_down(v, off);
    __shared__ float red[4];
    int lane = threadIdx.x & 63, wid = threadIdx.x >> 6;
    if (lane == 0) red[wid] = v;
    __syncthreads();
    if (threadIdx.x == 0) {
        float s = (red[0] + red[1]) + (red[2] + red[3]);
        atomicAdd(out, s * (1.0f / (float)TOT));
    }
}

__global__ void zero_kernel(float* out) { out[0] = 0.0f; }

extern "C" void kernel_launch(void* const* d_in, const int* in_sizes, int n_in,
                              void* d_out, int out_size, void* d_ws, size_t ws_size,
                              hipStream_t stream) {
    const float* x = (const float*)d_in[0];
    const float* y = (const float*)d_in[1];
    float* out = (float*)d_out;

    // ws layout: Arec 2MB | Brec 2MB | colpart 4MB | zeros 16B
    size_t need = ((size_t)8 << 20) + 16;
    if (ws_size >= need) {
        u16*   Arec    = (u16*)d_ws;
        u16*   Brec    = (u16*)((char*)d_ws + ((size_t)2 << 20));
        float* colpart = (float*)((char*)d_ws + ((size_t)4 << 20));
        float* zeros16 = (float*)((char*)d_ws + ((size_t)8 << 20));
        hipLaunchKernelGGL(pack_mfma, dim3(TWOTOT / 256), dim3(256), 0, stream,
                           x, y, Arec, Brec, zeros16, out);
        hipLaunchKernelGGL(chamfer_mfma, dim3(256), dim3(256), 0, stream,
                           Arec, Brec, zeros16, colpart, out);
        hipLaunchKernelGGL(colmin_pass2, dim3(TOT / 256), dim3(256), 0, stream,
                           colpart, out);
    } else {
        hipLaunchKernelGGL(zero_kernel, dim3(1), dim3(1), 0, stream, out);
        hipLaunchKernelGGL(chamfer_direct, dim3(512), dim3(256), 0, stream, x, y, out);
    }
}

// Round 15
// 44.268 us; speedup vs baseline: 1.3555x; 1.2879x over previous
//
#include <hip/hip_runtime.h>
#include <stdint.h>

#define BATCH 16
#define NPTS  4096
#define TOT   (BATCH * NPTS)     // 65536 points per tensor
#define TWOTOT (2 * TOT)

typedef float f4 __attribute__((ext_vector_type(4)));
typedef float f32x4 __attribute__((ext_vector_type(4)));
typedef short bh8 __attribute__((ext_vector_type(8)));   // 8 bf16 = 4 VGPR
typedef uint32_t u32;
typedef unsigned short u16;
typedef unsigned long long u64;

__device__ __forceinline__ u16 bfr(float f) {
    union { float f; u32 u; } v; v.f = f;
    u32 r = v.u + 0x7FFF + ((v.u >> 16) & 1);
    return (u16)(r >> 16);
}
__device__ __forceinline__ float bfback(u16 h) {
    union { u32 u; float f; } v; v.u = ((u32)h) << 16; return v.f;
}
#define BF16_ONE ((u16)0x3F80)

// d = min(a,b,c)
#define MIN3r(d, a, b, c) \
    asm("v_min3_f32 %0, %1, %2, %3" : "=v"(d) : "v"(a), "v"(b), "v"(c))
// acc = min(acc,u,v)
#define MIN3a(acc, u, v) \
    asm("v_min3_f32 %0, %1, %2, %0" : "+v"(acc) : "v"(u), "v"(v))

// pack: A-record per x-point, B-record per y-point (16 bf16 = 32B each).
//  A: [ahx,ahy,ahz, ahx,ahy,ahz, alx,aly, alz, x2h,x2l, 1,1, 0,0,0]   (A=-2x)
//  B: [yhx,yhy,yhz, ylx,yly,ylz, yhx,yhy, yhz, 1,1, y2h,y2l, 0,0,0]
// => sum_k A_k*B_k = Ah.Yh + Ah.Yl + Al.Yh + x2 + y2 == D[i,j]  (verified R14)
__global__ __launch_bounds__(256) void pack_mfma(const float* __restrict__ x,
                                                 const float* __restrict__ y,
                                                 u16* __restrict__ Arec,
                                                 u16* __restrict__ Brec,
                                                 float* __restrict__ zeros16,
                                                 float* __restrict__ out) {
    int idx = blockIdx.x * 256 + threadIdx.x;        // 0..2*TOT-1
    if (idx == 0) out[0] = 0.0f;
    if (idx == 1) { f4 z = {0.f, 0.f, 0.f, 0.f}; *(f4*)zeros16 = z; }

    bool isx = idx < TOT;
    int r = isx ? idx : (idx - TOT);
    const float* src = isx ? x : y;
    float a = src[r * 3 + 0];
    float b = src[r * 3 + 1];
    float c = src[r * 3 + 2];
    float s2 = fmaf(a, a, fmaf(b, b, c * c));
    u16 s2h = bfr(s2);
    u16 s2l = bfr(s2 - bfback(s2h));

    union { u16 h[16]; f4 v[2]; } rec;
    if (isx) {
        float ax = -2.0f * a, ay = -2.0f * b, az = -2.0f * c;
        u16 ahx = bfr(ax), ahy = bfr(ay), ahz = bfr(az);
        u16 alx = bfr(ax - bfback(ahx));
        u16 aly = bfr(ay - bfback(ahy));
        u16 alz = bfr(az - bfback(ahz));
        rec.h[0] = ahx;  rec.h[1] = ahy;  rec.h[2] = ahz;
        rec.h[3] = ahx;  rec.h[4] = ahy;  rec.h[5] = ahz;
        rec.h[6] = alx;  rec.h[7] = aly;
        rec.h[8] = alz;  rec.h[9] = s2h;  rec.h[10] = s2l;
        rec.h[11] = BF16_ONE; rec.h[12] = BF16_ONE;
        rec.h[13] = 0; rec.h[14] = 0; rec.h[15] = 0;
        f4* dst = (f4*)(Arec + (size_t)r * 16);
        dst[0] = rec.v[0]; dst[1] = rec.v[1];
    } else {
        u16 yhx = bfr(a), yhy = bfr(b), yhz = bfr(c);
        u16 ylx = bfr(a - bfback(yhx));
        u16 yly = bfr(b - bfback(yhy));
        u16 ylz = bfr(c - bfback(yhz));
        rec.h[0] = yhx;  rec.h[1] = yhy;  rec.h[2] = yhz;
        rec.h[3] = ylx;  rec.h[4] = yly;  rec.h[5] = ylz;
        rec.h[6] = yhx;  rec.h[7] = yhy;
        rec.h[8] = yhz;  rec.h[9] = BF16_ONE; rec.h[10] = BF16_ONE;
        rec.h[11] = s2h; rec.h[12] = s2l;
        rec.h[13] = 0; rec.h[14] = 0; rec.h[15] = 0;
        f4* dst = (f4*)(Brec + (size_t)r * 16);
        dst[0] = rec.v[0]; dst[1] = rec.v[1];
    }
}

#define GLOADB(B) do { \
    asm volatile("global_load_dwordx4 %0, %1, off" : "=v"(B) : "v"(baddr)); \
    baddr += bstep; \
} while (0)

#define WAITV(cnt, B) do { \
    asm volatile("s_waitcnt vmcnt(" cnt ")" : "+v"(B)); \
    __builtin_amdgcn_sched_barrier(0); \
} while (0)

#define MF4(P, BB) do { \
    P##0 = __builtin_amdgcn_mfma_f32_16x16x32_bf16(af0, BB, zc, 0, 0, 0); \
    P##1 = __builtin_amdgcn_mfma_f32_16x16x32_bf16(af1, BB, zc, 0, 0, 0); \
    P##2 = __builtin_amdgcn_mfma_f32_16x16x32_bf16(af2, BB, zc, 0, 0, 0); \
    P##3 = __builtin_amdgcn_mfma_f32_16x16x32_bf16(af3, BB, zc, 0, 0, 0); \
} while (0)

// col-min of one tile's 16 lane values -> cv (7 min3 + 1 fmin)
#define COLV(cv, P) do { \
    float t0,t1,t2,t3,t4,t5,t6; \
    MIN3r(t0, P##0[0], P##0[1], P##0[2]); \
    MIN3r(t1, P##0[3], P##1[0], P##1[1]); \
    MIN3r(t2, P##1[2], P##1[3], P##2[0]); \
    MIN3r(t3, P##2[1], P##2[2], P##2[3]); \
    MIN3r(t4, P##3[0], P##3[1], P##3[2]); \
    t5 = fminf(P##3[3], t0); \
    MIN3r(t6, t1, t2, t3); \
    MIN3r(cv, t4, t5, t6); \
} while (0)

// fused epilogue for TWO tiles: 16 min3 fold rows of both; 2 col-trees;
// 2 fire-and-forget ds_min (4 same-col lanes reduce in the LDS atomic unit).
#define EPI2(PA, PB) do { \
    MIN3a(r00, PA##0[0], PB##0[0]); MIN3a(r01, PA##0[1], PB##0[1]); \
    MIN3a(r02, PA##0[2], PB##0[2]); MIN3a(r03, PA##0[3], PB##0[3]); \
    MIN3a(r10, PA##1[0], PB##1[0]); MIN3a(r11, PA##1[1], PB##1[1]); \
    MIN3a(r12, PA##1[2], PB##1[2]); MIN3a(r13, PA##1[3], PB##1[3]); \
    MIN3a(r20, PA##2[0], PB##2[0]); MIN3a(r21, PA##2[1], PB##2[1]); \
    MIN3a(r22, PA##2[2], PB##2[2]); MIN3a(r23, PA##2[3], PB##2[3]); \
    MIN3a(r30, PA##3[0], PB##3[0]); MIN3a(r31, PA##3[1], PB##3[1]); \
    MIN3a(r32, PA##3[2], PB##3[2]); MIN3a(r33, PA##3[3], PB##3[3]); \
    float cvA, cvB; \
    COLV(cvA, PA); COLV(cvB, PB); \
    asm volatile("ds_min_f32 %0, %1" :: "v"(cma), "v"(cvA)); \
    asm volatile("ds_min_f32 %0, %1 offset:64" :: "v"(cma), "v"(cvB)); \
    cma += 128; \
} while (0)

// Block = (batch, 256-row i-chunk, 1024-col j-segment); 4 waves x 64 rows,
// A-stationary; streams 64 j-tiles with a 4-slot rotating B prefetch.
// Grid 1024 = 4 blocks/CU = 4 waves/SIMD (R14 was 1 -> stall-bound).
__global__ __launch_bounds__(256) void chamfer_mfma(const u16* __restrict__ Arec,
                                                    const u16* __restrict__ Brec,
                                                    const float* __restrict__ zeros16,
                                                    float* __restrict__ colpart,
                                                    float* __restrict__ rowpart) {
    __shared__ float colmin[NPTS / 4];
    int bid  = blockIdx.x;                 // [b:4][ic:4][jseg:2]
    int b    = bid >> 6;
    int ic   = (bid >> 2) & 15;
    int jseg = bid & 3;
    int tid  = threadIdx.x;
    int wv   = tid >> 6, lane = tid & 63;
    int lg   = lane >> 4, lm = lane & 15;

    for (int i = tid; i < NPTS / 4; i += 256) colmin[i] = 3.4e38f;

    int i0 = ic * 256 + wv * 64;
    int j0 = jseg * (NPTS / 4);

    // A frags: lane holds row lane&15, K-chunk (lane>>4)*8..+7; records are
    // 16 bf16 so only lg<2 carries data (K>=16 structurally zero).
    bh8 af0, af1, af2, af3;
    {
        bh8 z8 = {0, 0, 0, 0, 0, 0, 0, 0};
        const u16* ab = Arec + ((size_t)b * NPTS + i0 + lm) * 16 + lg * 8;
        af0 = (lg < 2) ? *(const bh8*)(ab + 0)   : z8;
        af1 = (lg < 2) ? *(const bh8*)(ab + 256) : z8;
        af2 = (lg < 2) ? *(const bh8*)(ab + 512) : z8;
        af3 = (lg < 2) ? *(const bh8*)(ab + 768) : z8;
    }
    __syncthreads();                       // colmin init + A loads ordered

    u64 baddr, bstep;
    {
        u64 real = (u64)(uintptr_t)(Brec + ((size_t)b * NPTS + j0 + lm) * 16 + lg * 8);
        u64 zadr = (u64)(uintptr_t)zeros16;
        baddr = (lg < 2) ? real : zadr;
        bstep = (lg < 2) ? (u64)512 : (u64)0;   // 16 points * 32B per tile
    }
    u32 cma = (u32)(uintptr_t)&colmin[0] + (u32)lm * 4;

    f32x4 zc = {0.f, 0.f, 0.f, 0.f};
    float r00=3.4e38f, r01=3.4e38f, r02=3.4e38f, r03=3.4e38f;
    float r10=3.4e38f, r11=3.4e38f, r12=3.4e38f, r13=3.4e38f;
    float r20=3.4e38f, r21=3.4e38f, r22=3.4e38f, r23=3.4e38f;
    float r30=3.4e38f, r31=3.4e38f, r32=3.4e38f, r33=3.4e38f;

    f32x4 aA0, aA1, aA2, aA3, aB0, aB1, aB2, aB3;
    bh8 b0, b1, b2, b3;

    GLOADB(b0); GLOADB(b1); GLOADB(b2); GLOADB(b3);   // tiles 0..3

    #pragma unroll 1
    for (int it = 0; it < 15; ++it) {      // 4 tiles/iter: tiles 4it..4it+3
        WAITV("3", b0); MF4(aA, b0); GLOADB(b0);
        WAITV("3", b1); MF4(aB, b1); GLOADB(b1);
        EPI2(aA, aB);
        WAITV("3", b2); MF4(aA, b2); GLOADB(b2);
        WAITV("3", b3); MF4(aB, b3); GLOADB(b3);
        EPI2(aA, aB);
    }
    // drain: tiles 60..63, no further loads
    WAITV("3", b0); MF4(aA, b0);
    WAITV("2", b1); MF4(aB, b1);
    EPI2(aA, aB);
    WAITV("1", b2); MF4(aA, b2);
    WAITV("0", b3); MF4(aB, b3);
    EPI2(aA, aB);

    // rowmin partial: reduce across the 16 col-lanes, write per-row values
    #define RRED(r) { r = fminf(r, __shfl_xor(r, 1)); r = fminf(r, __shfl_xor(r, 2)); \
                      r = fminf(r, __shfl_xor(r, 4)); r = fminf(r, __shfl_xor(r, 8)); }
    RRED(r00) RRED(r01) RRED(r02) RRED(r03)
    RRED(r10) RRED(r11) RRED(r12) RRED(r13)
    RRED(r20) RRED(r21) RRED(r22) RRED(r23)
    RRED(r30) RRED(r31) RRED(r32) RRED(r33)
    if (lm == 0) {
        float* rp = rowpart + (size_t)jseg * TOT + (size_t)b * NPTS + i0 + lg * 4;
        rp[0]  = r00; rp[1]  = r01; rp[2]  = r02; rp[3]  = r03;   // frag0
        rp[16] = r10; rp[17] = r11; rp[18] = r12; rp[19] = r13;   // frag1
        rp[32] = r20; rp[33] = r21; rp[34] = r22; rp[35] = r23;   // frag2
        rp[48] = r30; rp[49] = r31; rp[50] = r32; rp[51] = r33;   // frag3
    }

    __syncthreads();                       // all ds_min retired
    for (int j = tid; j < NPTS / 4; j += 256)
        colpart[(size_t)ic * TOT + (size_t)b * NPTS + j0 + j] = colmin[j];
}

// pass2: fold row partials (4 jseg) + col partials (16 ic), mean both.
__global__ __launch_bounds__(256) void chamfer_pass2(const float* __restrict__ rowpart,
                                                     const float* __restrict__ colpart,
                                                     float* __restrict__ out) {
    int t = blockIdx.x * 256 + threadIdx.x;           // (b,i)/(b,j) flattened
    float mr = rowpart[t];
    #pragma unroll
    for (int s = 1; s < 4; ++s) mr = fminf(mr, rowpart[(size_t)s * TOT + t]);
    float mc = colpart[t];
    #pragma unroll
    for (int ic = 1; ic < 16; ++ic) mc = fminf(mc, colpart[(size_t)ic * TOT + t]);

    float s = mr + mc;
    #pragma unroll
    for (int off = 32; off; off >>= 1) s += __shfl_down(s, off);
    __shared__ float red[4];
    int lane = threadIdx.x & 63, wid = threadIdx.x >> 6;
    if (lane == 0) red[wid] = s;
    __syncthreads();
    if (threadIdx.x == 0) {
        float tot = (red[0] + red[1]) + (red[2] + red[3]);
        atomicAdd(out, tot * (1.0f / (float)TOT));
    }
}

// ---------------- fallback (no workspace): direct form ----------------
__global__ __launch_bounds__(256) void chamfer_direct(const float* __restrict__ x,
                                                      const float* __restrict__ y,
                                                      float* __restrict__ out) {
    int blk = blockIdx.x;
    int dir = blk >> 8;
    int t = blk & 255;
    int b = t >> 4;
    int chunk = t & 15;
    const float* __restrict__ P = (dir ? y : x) + (b * NPTS + chunk * 256) * 3;
    const float* __restrict__ Q = (dir ? x : y) + b * NPTS * 3;
    float px = P[threadIdx.x * 3 + 0];
    float py = P[threadIdx.x * 3 + 1];
    float pz = P[threadIdx.x * 3 + 2];
    float b0 = 3.4e38f, b1 = 3.4e38f, b2 = 3.4e38f, b3 = 3.4e38f;
    for (int j = 0; j < NPTS; j += 4) {
        #pragma unroll
        for (int u = 0; u < 4; ++u) {
            float dx = px - Q[(j + u) * 3 + 0];
            float dy = py - Q[(j + u) * 3 + 1];
            float dz = pz - Q[(j + u) * 3 + 2];
            float d = fmaf(dx, dx, fmaf(dy, dy, dz * dz));
            if (u == 0) b0 = fminf(b0, d);
            if (u == 1) b1 = fminf(b1, d);
            if (u == 2) b2 = fminf(b2, d);
            if (u == 3) b3 = fminf(b3, d);
        }
    }
    float best = fminf(fminf(b0, b1), fminf(b2, b3));
    float v = best;
    #pragma unroll
    for (int off = 32; off; off >>= 1) v += __shfl_down(v, off);
    __shared__ float red[4];
    int lane = threadIdx.x & 63, wid = threadIdx.x >> 6;
    if (lane == 0) red[wid] = v;
    __syncthreads();
    if (threadIdx.x == 0) {
        float s = (red[0] + red[1]) + (red[2] + red[3]);
        atomicAdd(out, s * (1.0f / (float)TOT));
    }
}

__global__ void zero_kernel(float* out) { out[0] = 0.0f; }

extern "C" void kernel_launch(void* const* d_in, const int* in_sizes, int n_in,
                              void* d_out, int out_size, void* d_ws, size_t ws_size,
                              hipStream_t stream) {
    const float* x = (const float*)d_in[0];
    const float* y = (const float*)d_in[1];
    float* out = (float*)d_out;

    // ws: Arec 2MB | Brec 2MB | colpart 4MB | rowpart 1MB | zeros 16B
    size_t need = ((size_t)9 << 20) + 16;
    if (ws_size >= need) {
        u16*   Arec    = (u16*)d_ws;
        u16*   Brec    = (u16*)((char*)d_ws + ((size_t)2 << 20));
        float* colpart = (float*)((char*)d_ws + ((size_t)4 << 20));
        float* rowpart = (float*)((char*)d_ws + ((size_t)8 << 20));
        float* zeros16 = (float*)((char*)d_ws + ((size_t)9 << 20));
        hipLaunchKernelGGL(pack_mfma, dim3(TWOTOT / 256), dim3(256), 0, stream,
                           x, y, Arec, Brec, zeros16, out);
        hipLaunchKernelGGL(chamfer_mfma, dim3(1024), dim3(256), 0, stream,
                           Arec, Brec, zeros16, colpart, rowpart);
        hipLaunchKernelGGL(chamfer_pass2, dim3(TOT / 256), dim3(256), 0, stream,
                           rowpart, colpart, out);
    } else {
        hipLaunchKernelGGL(zero_kernel, dim3(1), dim3(1), 0, stream, out);
        hipLaunchKernelGGL(chamfer_direct, dim3(512), dim3(256), 0, stream, x, y, out);
    }
}

// Round 17
// 43.974 us; speedup vs baseline: 1.3645x; 1.0067x over previous
//
#include <hip/hip_runtime.h>
#include <stdint.h>

#define BATCH 16
#define NPTS  4096
#define TOT   (BATCH * NPTS)     // 65536 points per tensor
#define TWOTOT (2 * TOT)
#define JSEG  8                  // j-dimension split (8 blocks/CU)

typedef float f4 __attribute__((ext_vector_type(4)));
typedef float f32x4 __attribute__((ext_vector_type(4)));
typedef short bh8 __attribute__((ext_vector_type(8)));   // 8 bf16 = 4 VGPR
typedef uint32_t u32;
typedef unsigned short u16;
typedef unsigned long long u64;

__device__ __forceinline__ u16 bfr(float f) {
    union { float f; u32 u; } v; v.f = f;
    u32 r = v.u + 0x7FFF + ((v.u >> 16) & 1);
    return (u16)(r >> 16);
}
__device__ __forceinline__ float bfback(u16 h) {
    union { u32 u; float f; } v; v.u = ((u32)h) << 16; return v.f;
}
#define BF16_ONE ((u16)0x3F80)

#define MIN3r(d, a, b, c) \
    asm("v_min3_f32 %0, %1, %2, %3" : "=v"(d) : "v"(a), "v"(b), "v"(c))
#define MIN3a(acc, u, v) \
    asm("v_min3_f32 %0, %1, %2, %0" : "+v"(acc) : "v"(u), "v"(v))

// pack: A-record per x-point, B-record per y-point (16 bf16 = 32B each).
//  A: [ahx,ahy,ahz, ahx,ahy,ahz, alx,aly, alz, x2h,x2l, 1,1, 0,0,0]   (A=-2x)
//  B: [yhx,yhy,yhz, ylx,yly,ylz, yhx,yhy, yhz, 1,1, y2h,y2l, 0,0,0]
// => sum_k A_k*B_k = Ah.Yh + Ah.Yl + Al.Yh + x2 + y2 == D[i,j]  (verified R14)
__global__ __launch_bounds__(256) void pack_mfma(const float* __restrict__ x,
                                                 const float* __restrict__ y,
                                                 u16* __restrict__ Arec,
                                                 u16* __restrict__ Brec,
                                                 float* __restrict__ zeros16,
                                                 float* __restrict__ out) {
    int idx = blockIdx.x * 256 + threadIdx.x;        // 0..2*TOT-1
    if (idx == 0) out[0] = 0.0f;
    if (idx == 1) { f4 z = {0.f, 0.f, 0.f, 0.f}; *(f4*)zeros16 = z; }

    bool isx = idx < TOT;
    int r = isx ? idx : (idx - TOT);
    const float* src = isx ? x : y;
    float a = src[r * 3 + 0];
    float b = src[r * 3 + 1];
    float c = src[r * 3 + 2];
    float s2 = fmaf(a, a, fmaf(b, b, c * c));
    u16 s2h = bfr(s2);
    u16 s2l = bfr(s2 - bfback(s2h));

    union { u16 h[16]; f4 v[2]; } rec;
    if (isx) {
        float ax = -2.0f * a, ay = -2.0f * b, az = -2.0f * c;
        u16 ahx = bfr(ax), ahy = bfr(ay), ahz = bfr(az);
        u16 alx = bfr(ax - bfback(ahx));
        u16 aly = bfr(ay - bfback(ahy));
        u16 alz = bfr(az - bfback(ahz));
        rec.h[0] = ahx;  rec.h[1] = ahy;  rec.h[2] = ahz;
        rec.h[3] = ahx;  rec.h[4] = ahy;  rec.h[5] = ahz;
        rec.h[6] = alx;  rec.h[7] = aly;
        rec.h[8] = alz;  rec.h[9] = s2h;  rec.h[10] = s2l;
        rec.h[11] = BF16_ONE; rec.h[12] = BF16_ONE;
        rec.h[13] = 0; rec.h[14] = 0; rec.h[15] = 0;
        f4* dst = (f4*)(Arec + (size_t)r * 16);
        dst[0] = rec.v[0]; dst[1] = rec.v[1];
    } else {
        u16 yhx = bfr(a), yhy = bfr(b), yhz = bfr(c);
        u16 ylx = bfr(a - bfback(yhx));
        u16 yly = bfr(b - bfback(yhy));
        u16 ylz = bfr(c - bfback(yhz));
        rec.h[0] = yhx;  rec.h[1] = yhy;  rec.h[2] = yhz;
        rec.h[3] = ylx;  rec.h[4] = yly;  rec.h[5] = ylz;
        rec.h[6] = yhx;  rec.h[7] = yhy;
        rec.h[8] = yhz;  rec.h[9] = BF16_ONE; rec.h[10] = BF16_ONE;
        rec.h[11] = s2h; rec.h[12] = s2l;
        rec.h[13] = 0; rec.h[14] = 0; rec.h[15] = 0;
        f4* dst = (f4*)(Brec + (size_t)r * 16);
        dst[0] = rec.v[0]; dst[1] = rec.v[1];
    }
}

#define GLOADB(B) do { \
    asm volatile("global_load_dwordx4 %0, %1, off" : "=v"(B) : "v"(baddr)); \
    baddr += bstep; \
} while (0)

#define WAITV(cnt, B) do { \
    asm volatile("s_waitcnt vmcnt(" cnt ")" : "+v"(B)); \
    __builtin_amdgcn_sched_barrier(0); \
} while (0)

#define MF4(P, BB) do { \
    P##0 = __builtin_amdgcn_mfma_f32_16x16x32_bf16(af0, BB, zc, 0, 0, 0); \
    P##1 = __builtin_amdgcn_mfma_f32_16x16x32_bf16(af1, BB, zc, 0, 0, 0); \
    P##2 = __builtin_amdgcn_mfma_f32_16x16x32_bf16(af2, BB, zc, 0, 0, 0); \
    P##3 = __builtin_amdgcn_mfma_f32_16x16x32_bf16(af3, BB, zc, 0, 0, 0); \
} while (0)

// col-min of one tile's 16 lane values -> cv (7 min3 + 1 fmin)
#define COLV(cv, P) do { \
    float t0,t1,t2,t3,t4,t5,t6; \
    MIN3r(t0, P##0[0], P##0[1], P##0[2]); \
    MIN3r(t1, P##0[3], P##1[0], P##1[1]); \
    MIN3r(t2, P##1[2], P##1[3], P##2[0]); \
    MIN3r(t3, P##2[1], P##2[2], P##2[3]); \
    MIN3r(t4, P##3[0], P##3[1], P##3[2]); \
    t5 = fminf(P##3[3], t0); \
    MIN3r(t6, t1, t2, t3); \
    MIN3r(cv, t4, t5, t6); \
} while (0)

// fused epilogue for TWO tiles (verified R15)
#define EPI2(PA, PB) do { \
    MIN3a(r00, PA##0[0], PB##0[0]); MIN3a(r01, PA##0[1], PB##0[1]); \
    MIN3a(r02, PA##0[2], PB##0[2]); MIN3a(r03, PA##0[3], PB##0[3]); \
    MIN3a(r10, PA##1[0], PB##1[0]); MIN3a(r11, PA##1[1], PB##1[1]); \
    MIN3a(r12, PA##1[2], PB##1[2]); MIN3a(r13, PA##1[3], PB##1[3]); \
    MIN3a(r20, PA##2[0], PB##2[0]); MIN3a(r21, PA##2[1], PB##2[1]); \
    MIN3a(r22, PA##2[2], PB##2[2]); MIN3a(r23, PA##2[3], PB##2[3]); \
    MIN3a(r30, PA##3[0], PB##3[0]); MIN3a(r31, PA##3[1], PB##3[1]); \
    MIN3a(r32, PA##3[2], PB##3[2]); MIN3a(r33, PA##3[3], PB##3[3]); \
    float cvA, cvB; \
    COLV(cvA, PA); COLV(cvB, PB); \
    asm volatile("ds_min_f32 %0, %1" :: "v"(cma), "v"(cvA)); \
    asm volatile("ds_min_f32 %0, %1 offset:64" :: "v"(cma), "v"(cvB)); \
    cma += 128; \
} while (0)

// Block = (batch, 256-row i-chunk, 512-col j-segment); 4 waves x 64 rows,
// A-stationary; streams NTILES=32 j-tiles with a 4-slot rotating B prefetch.
// Grid 2048 = 8 blocks/CU = 8 waves/SIMD.
__global__ __launch_bounds__(256) void chamfer_mfma(const u16* __restrict__ Arec,
                                                    const u16* __restrict__ Brec,
                                                    const float* __restrict__ zeros16,
                                                    float* __restrict__ colpart,
                                                    float* __restrict__ rowpart) {
    constexpr int QLEN   = NPTS / JSEG;     // 512 cols per segment
    constexpr int NTILES = QLEN / 16;       // 32 tiles
    constexpr int NITER  = NTILES / 4 - 1;  // 7 full iterations (4 tiles each)

    __shared__ float colmin[QLEN];
    int bid  = blockIdx.x;                 // [b:16][ic:16][jseg:8]
    int b    = bid >> 7;
    int ic   = (bid >> 3) & 15;
    int jseg = bid & 7;
    int tid  = threadIdx.x;
    int wv   = tid >> 6, lane = tid & 63;
    int lg   = lane >> 4, lm = lane & 15;

    for (int i = tid; i < QLEN; i += 256) colmin[i] = 3.4e38f;

    int i0 = ic * 256 + wv * 64;
    int j0 = jseg * QLEN;

    // A frags: lane holds row lane&15, K-chunk (lane>>4)*8..+7; records are
    // 16 bf16 so only lg<2 carries data (K>=16 structurally zero).
    bh8 af0, af1, af2, af3;
    {
        bh8 z8 = {0, 0, 0, 0, 0, 0, 0, 0};
        const u16* ab = Arec + ((size_t)b * NPTS + i0 + lm) * 16 + lg * 8;
        af0 = (lg < 2) ? *(const bh8*)(ab + 0)   : z8;
        af1 = (lg < 2) ? *(const bh8*)(ab + 256) : z8;
        af2 = (lg < 2) ? *(const bh8*)(ab + 512) : z8;
        af3 = (lg < 2) ? *(const bh8*)(ab + 768) : z8;
    }
    __syncthreads();                       // colmin init + A loads ordered

    u64 baddr, bstep;
    {
        u64 real = (u64)(uintptr_t)(Brec + ((size_t)b * NPTS + j0 + lm) * 16 + lg * 8);
        u64 zadr = (u64)(uintptr_t)zeros16;
        baddr = (lg < 2) ? real : zadr;
        bstep = (lg < 2) ? (u64)512 : (u64)0;   // 16 points * 32B per tile
    }
    u32 cma = (u32)(uintptr_t)&colmin[0] + (u32)lm * 4;

    f32x4 zc = {0.f, 0.f, 0.f, 0.f};
    float r00=3.4e38f, r01=3.4e38f, r02=3.4e38f, r03=3.4e38f;
    float r10=3.4e38f, r11=3.4e38f, r12=3.4e38f, r13=3.4e38f;
    float r20=3.4e38f, r21=3.4e38f, r22=3.4e38f, r23=3.4e38f;
    float r30=3.4e38f, r31=3.4e38f, r32=3.4e38f, r33=3.4e38f;

    f32x4 aA0, aA1, aA2, aA3, aB0, aB1, aB2, aB3;
    bh8 b0, b1, b2, b3;

    GLOADB(b0); GLOADB(b1); GLOADB(b2); GLOADB(b3);   // tiles 0..3

    #pragma unroll 1
    for (int it = 0; it < NITER; ++it) {   // 4 tiles per iteration
        WAITV("3", b0); MF4(aA, b0); GLOADB(b0);
        WAITV("3", b1); MF4(aB, b1); GLOADB(b1);
        EPI2(aA, aB);
        WAITV("3", b2); MF4(aA, b2); GLOADB(b2);
        WAITV("3", b3); MF4(aB, b3); GLOADB(b3);
        EPI2(aA, aB);
    }
    // drain: last 4 tiles, no further loads
    WAITV("3", b0); MF4(aA, b0);
    WAITV("2", b1); MF4(aB, b1);
    EPI2(aA, aB);
    WAITV("1", b2); MF4(aA, b2);
    WAITV("0", b3); MF4(aB, b3);
    EPI2(aA, aB);

    // rowmin partial: reduce across the 16 col-lanes, write per-row values
    #define RRED(r) { r = fminf(r, __shfl_xor(r, 1)); r = fminf(r, __shfl_xor(r, 2)); \
                      r = fminf(r, __shfl_xor(r, 4)); r = fminf(r, __shfl_xor(r, 8)); }
    RRED(r00) RRED(r01) RRED(r02) RRED(r03)
    RRED(r10) RRED(r11) RRED(r12) RRED(r13)
    RRED(r20) RRED(r21) RRED(r22) RRED(r23)
    RRED(r30) RRED(r31) RRED(r32) RRED(r33)
    if (lm == 0) {
        float* rp = rowpart + (size_t)jseg * TOT + (size_t)b * NPTS + i0 + lg * 4;
        rp[0]  = r00; rp[1]  = r01; rp[2]  = r02; rp[3]  = r03;
        rp[16] = r10; rp[17] = r11; rp[18] = r12; rp[19] = r13;
        rp[32] = r20; rp[33] = r21; rp[34] = r22; rp[35] = r23;
        rp[48] = r30; rp[49] = r31; rp[50] = r32; rp[51] = r33;
    }

    __syncthreads();                       // all ds_min retired
    for (int j = tid; j < QLEN; j += 256)
        colpart[(size_t)ic * TOT + (size_t)b * NPTS + j0 + j] = colmin[j];
}

// pass2: fold row partials (JSEG) + col partials (16 ic), mean both.
__global__ __launch_bounds__(256) void chamfer_pass2(const float* __restrict__ rowpart,
                                                     const float* __restrict__ colpart,
                                                     float* __restrict__ out) {
    int t = blockIdx.x * 256 + threadIdx.x;           // (b,i)/(b,j) flattened
    float mr = rowpart[t];
    #pragma unroll
    for (int s = 1; s < JSEG; ++s) mr = fminf(mr, rowpart[(size_t)s * TOT + t]);
    float mc = colpart[t];
    #pragma unroll
    for (int ic = 1; ic < 16; ++ic) mc = fminf(mc, colpart[(size_t)ic * TOT + t]);

    float s = mr + mc;
    #pragma unroll
    for (int off = 32; off; off >>= 1) s += __shfl_down(s, off);
    __shared__ float red[4];
    int lane = threadIdx.x & 63, wid = threadIdx.x >> 6;
    if (lane == 0) red[wid] = s;
    __syncthreads();
    if (threadIdx.x == 0) {
        float tot = (red[0] + red[1]) + (red[2] + red[3]);
        atomicAdd(out, tot * (1.0f / (float)TOT));
    }
}

// ---------------- fallback (no workspace): direct form ----------------
__global__ __launch_bounds__(256) void chamfer_direct(const float* __restrict__ x,
                                                      const float* __restrict__ y,
                                                      float* __restrict__ out) {
    int blk = blockIdx.x;
    int dir = blk >> 8;
    int t = blk & 255;
    int b = t >> 4;
    int chunk = t & 15;
    const float* __restrict__ P = (dir ? y : x) + (b * NPTS + chunk * 256) * 3;
    const float* __restrict__ Q = (dir ? x : y) + b * NPTS * 3;
    float px = P[threadIdx.x * 3 + 0];
    float py = P[threadIdx.x * 3 + 1];
    float pz = P[threadIdx.x * 3 + 2];
    float b0 = 3.4e38f, b1 = 3.4e38f, b2 = 3.4e38f, b3 = 3.4e38f;
    for (int j = 0; j < NPTS; j += 4) {
        #pragma unroll
        for (int u = 0; u < 4; ++u) {
            float dx = px - Q[(j + u) * 3 + 0];
            float dy = py - Q[(j + u) * 3 + 1];
            float dz = pz - Q[(j + u) * 3 + 2];
            float d = fmaf(dx, dx, fmaf(dy, dy, dz * dz));
            if (u == 0) b0 = fminf(b0, d);
            if (u == 1) b1 = fminf(b1, d);
            if (u == 2) b2 = fminf(b2, d);
            if (u == 3) b3 = fminf(b3, d);
        }
    }
    float best = fminf(fminf(b0, b1), fminf(b2, b3));
    float v = best;
    #pragma unroll
    for (int off = 32; off; off >>= 1) v += __shfl_down(v, off);
    __shared__ float red[4];
    int lane = threadIdx.x & 63, wid = threadIdx.x >> 6;
    if (lane == 0) red[wid] = v;
    __syncthreads();
    if (threadIdx.x == 0) {
        float s = (red[0] + red[1]) + (red[2] + red[3]);
        atomicAdd(out, s * (1.0f / (float)TOT));
    }
}

__global__ void zero_kernel(float* out) { out[0] = 0.0f; }

extern "C" void kernel_launch(void* const* d_in, const int* in_sizes, int n_in,
                              void* d_out, int out_size, void* d_ws, size_t ws_size,
                              hipStream_t stream) {
    const float* x = (const float*)d_in[0];
    const float* y = (const float*)d_in[1];
    float* out = (float*)d_out;

    // ws: Arec 2MB | Brec 2MB | colpart 4MB | rowpart 2MB | zeros 16B
    size_t need = ((size_t)10 << 20) + 16;
    if (ws_size >= need) {
        u16*   Arec    = (u16*)d_ws;
        u16*   Brec    = (u16*)((char*)d_ws + ((size_t)2 << 20));
        float* colpart = (float*)((char*)d_ws + ((size_t)4 << 20));
        float* rowpart = (float*)((char*)d_ws + ((size_t)8 << 20));
        float* zeros16 = (float*)((char*)d_ws + ((size_t)10 << 20));
        hipLaunchKernelGGL(pack_mfma, dim3(TWOTOT / 256), dim3(256), 0, stream,
                           x, y, Arec, Brec, zeros16, out);
        hipLaunchKernelGGL(chamfer_mfma, dim3(16 * 16 * JSEG), dim3(256), 0, stream,
                           Arec, Brec, zeros16, colpart, rowpart);
        hipLaunchKernelGGL(chamfer_pass2, dim3(TOT / 256), dim3(256), 0, stream,
                           rowpart, colpart, out);
    } else {
        hipLaunchKernelGGL(zero_kernel, dim3(1), dim3(1), 0, stream, out);
        hipLaunchKernelGGL(chamfer_direct, dim3(512), dim3(256), 0, stream, x, y, out);
    }
}

// Round 18
// 43.309 us; speedup vs baseline: 1.3855x; 1.0154x over previous
//
#include <hip/hip_runtime.h>
#include <stdint.h>

#define BATCH 16
#define NPTS  4096
#define TOT   (BATCH * NPTS)     // 65536 points per tensor
#define TWOTOT (2 * TOT)
#define JSEG  8

typedef float f4 __attribute__((ext_vector_type(4)));
typedef float f32x4 __attribute__((ext_vector_type(4)));
typedef short bh8 __attribute__((ext_vector_type(8)));   // 8 bf16 = 4 VGPR
typedef uint32_t u32;
typedef unsigned short u16;

__device__ __forceinline__ u16 bfr(float f) {
    union { float f; u32 u; } v; v.f = f;
    u32 r = v.u + 0x7FFF + ((v.u >> 16) & 1);
    return (u16)(r >> 16);
}
__device__ __forceinline__ float bfback(u16 h) {
    union { u32 u; float f; } v; v.u = ((u32)h) << 16; return v.f;
}
#define BF16_ONE ((u16)0x3F80)

#define MIN3r(d, a, b, c) \
    asm("v_min3_f32 %0, %1, %2, %3" : "=v"(d) : "v"(a), "v"(b), "v"(c))
#define MIN3a(acc, u, v) \
    asm("v_min3_f32 %0, %1, %2, %0" : "+v"(acc) : "v"(u), "v"(v))

// pack: A-record per x-point, B-record per y-point (16 bf16 = 32B each).
//  A: [ahx,ahy,ahz, ahx,ahy,ahz, alx,aly, alz, x2h,x2l, 1,1, 0,0,0]   (A=-2x)
//  B: [yhx,yhy,yhz, ylx,yly,ylz, yhx,yhy, yhz, 1,1, y2h,y2l, 0,0,0]
// => sum_k A_k*B_k = Ah.Yh + Ah.Yl + Al.Yh + x2 + y2 == D[i,j]  (verified R14)
__global__ __launch_bounds__(256) void pack_mfma(const float* __restrict__ x,
                                                 const float* __restrict__ y,
                                                 u16* __restrict__ Arec,
                                                 u16* __restrict__ Brec,
                                                 float* __restrict__ out) {
    int idx = blockIdx.x * 256 + threadIdx.x;        // 0..2*TOT-1
    if (idx == 0) out[0] = 0.0f;

    bool isx = idx < TOT;
    int r = isx ? idx : (idx - TOT);
    const float* src = isx ? x : y;
    float a = src[r * 3 + 0];
    float b = src[r * 3 + 1];
    float c = src[r * 3 + 2];
    float s2 = fmaf(a, a, fmaf(b, b, c * c));
    u16 s2h = bfr(s2);
    u16 s2l = bfr(s2 - bfback(s2h));

    union { u16 h[16]; f4 v[2]; } rec;
    if (isx) {
        float ax = -2.0f * a, ay = -2.0f * b, az = -2.0f * c;
        u16 ahx = bfr(ax), ahy = bfr(ay), ahz = bfr(az);
        u16 alx = bfr(ax - bfback(ahx));
        u16 aly = bfr(ay - bfback(ahy));
        u16 alz = bfr(az - bfback(ahz));
        rec.h[0] = ahx;  rec.h[1] = ahy;  rec.h[2] = ahz;
        rec.h[3] = ahx;  rec.h[4] = ahy;  rec.h[5] = ahz;
        rec.h[6] = alx;  rec.h[7] = aly;
        rec.h[8] = alz;  rec.h[9] = s2h;  rec.h[10] = s2l;
        rec.h[11] = BF16_ONE; rec.h[12] = BF16_ONE;
        rec.h[13] = 0; rec.h[14] = 0; rec.h[15] = 0;
        f4* dst = (f4*)(Arec + (size_t)r * 16);
        dst[0] = rec.v[0]; dst[1] = rec.v[1];
    } else {
        u16 yhx = bfr(a), yhy = bfr(b), yhz = bfr(c);
        u16 ylx = bfr(a - bfback(yhx));
        u16 yly = bfr(b - bfback(yhy));
        u16 ylz = bfr(c - bfback(yhz));
        rec.h[0] = yhx;  rec.h[1] = yhy;  rec.h[2] = yhz;
        rec.h[3] = ylx;  rec.h[4] = yly;  rec.h[5] = ylz;
        rec.h[6] = yhx;  rec.h[7] = yhy;
        rec.h[8] = yhz;  rec.h[9] = BF16_ONE; rec.h[10] = BF16_ONE;
        rec.h[11] = s2h; rec.h[12] = s2l;
        rec.h[13] = 0; rec.h[14] = 0; rec.h[15] = 0;
        f4* dst = (f4*)(Brec + (size_t)r * 16);
        dst[0] = rec.v[0]; dst[1] = rec.v[1];
    }
}

// LDS frag read, immediate offset (tile*512 within the 16KB stage)
#define DSRL(dst, base, imm) \
    asm volatile("ds_read_b128 %0, %1 offset:" imm : "=v"(dst) : "v"(base))

// counted lgkm wait; ties the slot so dependent MFMA can't hoist (rule #18)
#define WAITL(cnt, slot) do { \
    asm volatile("s_waitcnt lgkmcnt(" cnt ")" : "+v"(slot)); \
    __builtin_amdgcn_sched_barrier(0); \
} while (0)

#define MF4(P, BB) do { \
    P##0 = __builtin_amdgcn_mfma_f32_16x16x32_bf16(af0, BB, zc, 0, 0, 0); \
    P##1 = __builtin_amdgcn_mfma_f32_16x16x32_bf16(af1, BB, zc, 0, 0, 0); \
    P##2 = __builtin_amdgcn_mfma_f32_16x16x32_bf16(af2, BB, zc, 0, 0, 0); \
    P##3 = __builtin_amdgcn_mfma_f32_16x16x32_bf16(af3, BB, zc, 0, 0, 0); \
} while (0)

// col-min of one tile's 16 lane values -> cv (7 min3 + 1 fmin)
#define COLV(cv, P) do { \
    float t0,t1,t2,t3,t4,t5,t6; \
    MIN3r(t0, P##0[0], P##0[1], P##0[2]); \
    MIN3r(t1, P##0[3], P##1[0], P##1[1]); \
    MIN3r(t2, P##1[2], P##1[3], P##2[0]); \
    MIN3r(t3, P##2[1], P##2[2], P##2[3]); \
    MIN3r(t4, P##3[0], P##3[1], P##3[2]); \
    t5 = fminf(P##3[3], t0); \
    MIN3r(t6, t1, t2, t3); \
    MIN3r(cv, t4, t5, t6); \
} while (0)

// fused epilogue for TWO tiles (verified R15); ds_min joins the lgkm queue
// AFTER the already-issued frag reads (in-order) - accounted in wait counts.
#define EPI2(PA, PB) do { \
    MIN3a(r00, PA##0[0], PB##0[0]); MIN3a(r01, PA##0[1], PB##0[1]); \
    MIN3a(r02, PA##0[2], PB##0[2]); MIN3a(r03, PA##0[3], PB##0[3]); \
    MIN3a(r10, PA##1[0], PB##1[0]); MIN3a(r11, PA##1[1], PB##1[1]); \
    MIN3a(r12, PA##1[2], PB##1[2]); MIN3a(r13, PA##1[3], PB##1[3]); \
    MIN3a(r20, PA##2[0], PB##2[0]); MIN3a(r21, PA##2[1], PB##2[1]); \
    MIN3a(r22, PA##2[2], PB##2[2]); MIN3a(r23, PA##2[3], PB##2[3]); \
    MIN3a(r30, PA##3[0], PB##3[0]); MIN3a(r31, PA##3[1], PB##3[1]); \
    MIN3a(r32, PA##3[2], PB##3[2]); MIN3a(r33, PA##3[3], PB##3[3]); \
    float cvA, cvB; \
    COLV(cvA, PA); COLV(cvB, PB); \
    asm volatile("ds_min_f32 %0, %1" :: "v"(cma), "v"(cvA)); \
    asm volatile("ds_min_f32 %0, %1 offset:64" :: "v"(cma), "v"(cvB)); \
    cma += 128; \
} while (0)

// Block = (batch, 256-row i-chunk, 512-col j-segment); 4 waves, A-stationary.
// B segment staged ONCE to LDS (coalesced 16KB); per-tile frags come from
// ds_read_b128 broadcast with a 6-slot rotating pipeline and hand-verified
// counted lgkmcnt waits (reads and ds_mins share the in-order DS queue).
__global__ __launch_bounds__(256) void chamfer_mfma(const u16* __restrict__ Arec,
                                                    const u16* __restrict__ Brec,
                                                    float* __restrict__ colpart,
                                                    float* __restrict__ rowpart) {
    constexpr int QLEN = NPTS / JSEG;       // 512 cols
    __shared__ u16  Bst[QLEN * 16];         // 16 KB
    __shared__ float colmin[QLEN];          // 2 KB

    int bid  = blockIdx.x;                 // [b:16][ic:16][jseg:8]
    int b    = bid >> 7;
    int ic   = (bid >> 3) & 15;
    int jseg = bid & 7;
    int tid  = threadIdx.x;
    int wv   = tid >> 6, lane = tid & 63;
    int lg   = lane >> 4, lm = lane & 15;

    int i0 = ic * 256 + wv * 64;
    int j0 = jseg * QLEN;

    // stage B segment: 512 recs * 32B = 16KB, 64B per thread, coalesced
    {
        const f4* src = (const f4*)(Brec + ((size_t)b * NPTS + j0) * 16);
        f4* dst = (f4*)Bst;
        int t4 = tid * 4;
        f4 v0 = src[t4 + 0], v1 = src[t4 + 1], v2 = src[t4 + 2], v3 = src[t4 + 3];
        dst[t4 + 0] = v0; dst[t4 + 1] = v1; dst[t4 + 2] = v2; dst[t4 + 3] = v3;
    }
    for (int i = tid; i < QLEN; i += 256) colmin[i] = 3.4e38f;

    // A frags: lane = row lm, K-chunk lg*8..+7; only lg<2 carries data
    // (K>=16 products hit A=0, so upper-lane B content is irrelevant).
    bh8 af0, af1, af2, af3;
    {
        bh8 z8 = {0, 0, 0, 0, 0, 0, 0, 0};
        const u16* ab = Arec + ((size_t)b * NPTS + i0 + lm) * 16 + lg * 8;
        af0 = (lg < 2) ? *(const bh8*)(ab + 0)   : z8;
        af1 = (lg < 2) ? *(const bh8*)(ab + 256) : z8;
        af2 = (lg < 2) ? *(const bh8*)(ab + 512) : z8;
        af3 = (lg < 2) ? *(const bh8*)(ab + 768) : z8;
    }
    __syncthreads();                       // staging + colmin init complete

    // frag address: rec (tile*16+lm), half lg; upper lanes read offset 0 (junk, OK)
    u32 lofs = (u32)(uintptr_t)&Bst[0] + ((lg < 2) ? (u32)(lm * 32 + lg * 16) : 0u);
    u32 cma  = (u32)(uintptr_t)&colmin[0] + (u32)lm * 4;

    f32x4 zc = {0.f, 0.f, 0.f, 0.f};
    float r00=3.4e38f, r01=3.4e38f, r02=3.4e38f, r03=3.4e38f;
    float r10=3.4e38f, r11=3.4e38f, r12=3.4e38f, r13=3.4e38f;
    float r20=3.4e38f, r21=3.4e38f, r22=3.4e38f, r23=3.4e38f;
    float r30=3.4e38f, r31=3.4e38f, r32=3.4e38f, r33=3.4e38f;

    f32x4 aA0, aA1, aA2, aA3, aB0, aB1, aB2, aB3;
    bh8 s0, s1, s2, s3, s4, s5;

    // prologue: tiles 0..5 (tile stride 512B)
    DSRL(s0, lofs, "0");    DSRL(s1, lofs, "512");
    DSRL(s2, lofs, "1024"); DSRL(s3, lofs, "1536");
    DSRL(s4, lofs, "2048"); DSRL(s5, lofs, "2560");

    // unit 0: tiles 0,1 ; prefetch t6,t7
    WAITL("5", s0); MF4(aA, s0); DSRL(s0, lofs, "3072");
    WAITL("5", s1); MF4(aB, s1); DSRL(s1, lofs, "3584");
    EPI2(aA, aB);

    u32 lofs2 = lofs + 4096;               // prefetch base = tile 8
    #pragma unroll 1
    for (int k = 0; k < 4; ++k) {          // 3 units (6 tiles) per iteration
        WAITL("7", s2); MF4(aA, s2); DSRL(s2, lofs2, "0");
        WAITL("7", s3); MF4(aB, s3); DSRL(s3, lofs2, "512");
        EPI2(aA, aB);
        WAITL("7", s4); MF4(aA, s4); DSRL(s4, lofs2, "1024");
        WAITL("7", s5); MF4(aB, s5); DSRL(s5, lofs2, "1536");
        EPI2(aA, aB);
        WAITL("7", s0); MF4(aA, s0); DSRL(s0, lofs2, "2048");
        WAITL("7", s1); MF4(aB, s1); DSRL(s1, lofs2, "2560");
        EPI2(aA, aB);
        lofs2 += 3072;
    }
    // drain: tiles 26..31 in slots s2..s5,s0,s1 (wait counts hand-simulated)
    WAITL("7", s2); MF4(aA, s2);
    WAITL("6", s3); MF4(aB, s3);
    EPI2(aA, aB);
    WAITL("7", s4); MF4(aA, s4);
    WAITL("5", s5); MF4(aB, s5);
    EPI2(aA, aB);
    WAITL("4", s0); MF4(aA, s0);
    WAITL("0", s1); MF4(aB, s1);
    EPI2(aA, aB);

    // rowmin partial: reduce across the 16 col-lanes, write per-row values
    #define RRED(r) { r = fminf(r, __shfl_xor(r, 1)); r = fminf(r, __shfl_xor(r, 2)); \
                      r = fminf(r, __shfl_xor(r, 4)); r = fminf(r, __shfl_xor(r, 8)); }
    RRED(r00) RRED(r01) RRED(r02) RRED(r03)
    RRED(r10) RRED(r11) RRED(r12) RRED(r13)
    RRED(r20) RRED(r21) RRED(r22) RRED(r23)
    RRED(r30) RRED(r31) RRED(r32) RRED(r33)
    if (lm == 0) {
        float* rp = rowpart + (size_t)jseg * TOT + (size_t)b * NPTS + i0 + lg * 4;
        rp[0]  = r00; rp[1]  = r01; rp[2]  = r02; rp[3]  = r03;
        rp[16] = r10; rp[17] = r11; rp[18] = r12; rp[19] = r13;
        rp[32] = r20; rp[33] = r21; rp[34] = r22; rp[35] = r23;
        rp[48] = r30; rp[49] = r31; rp[50] = r32; rp[51] = r33;
    }

    __syncthreads();                       // all ds_min retired
    for (int j = tid; j < QLEN; j += 256)
        colpart[(size_t)ic * TOT + (size_t)b * NPTS + j0 + j] = colmin[j];
}

// pass2: fold row partials (JSEG) + col partials (16 ic), mean both.
__global__ __launch_bounds__(256) void chamfer_pass2(const float* __restrict__ rowpart,
                                                     const float* __restrict__ colpart,
                                                     float* __restrict__ out) {
    int t = blockIdx.x * 256 + threadIdx.x;
    float mr = rowpart[t];
    #pragma unroll
    for (int s = 1; s < JSEG; ++s) mr = fminf(mr, rowpart[(size_t)s * TOT + t]);
    float mc = colpart[t];
    #pragma unroll
    for (int ic = 1; ic < 16; ++ic) mc = fminf(mc, colpart[(size_t)ic * TOT + t]);

    float s = mr + mc;
    #pragma unroll
    for (int off = 32; off; off >>= 1) s += __shfl_down(s, off);
    __shared__ float red[4];
    int lane = threadIdx.x & 63, wid = threadIdx.x >> 6;
    if (lane == 0) red[wid] = s;
    __syncthreads();
    if (threadIdx.x == 0) {
        float tot = (red[0] + red[1]) + (red[2] + red[3]);
        atomicAdd(out, tot * (1.0f / (float)TOT));
    }
}

// ---------------- fallback (no workspace): direct form ----------------
__global__ __launch_bounds__(256) void chamfer_direct(const float* __restrict__ x,
                                                      const float* __restrict__ y,
                                                      float* __restrict__ out) {
    int blk = blockIdx.x;
    int dir = blk >> 8;
    int t = blk & 255;
    int b = t >> 4;
    int chunk = t & 15;
    const float* __restrict__ P = (dir ? y : x) + (b * NPTS + chunk * 256) * 3;
    const float* __restrict__ Q = (dir ? x : y) + b * NPTS * 3;
    float px = P[threadIdx.x * 3 + 0];
    float py = P[threadIdx.x * 3 + 1];
    float pz = P[threadIdx.x * 3 + 2];
    float b0 = 3.4e38f, b1 = 3.4e38f, b2 = 3.4e38f, b3 = 3.4e38f;
    for (int j = 0; j < NPTS; j += 4) {
        #pragma unroll
        for (int u = 0; u < 4; ++u) {
            float dx = px - Q[(j + u) * 3 + 0];
            float dy = py - Q[(j + u) * 3 + 1];
            float dz = pz - Q[(j + u) * 3 + 2];
            float d = fmaf(dx, dx, fmaf(dy, dy, dz * dz));
            if (u == 0) b0 = fminf(b0, d);
            if (u == 1) b1 = fminf(b1, d);
            if (u == 2) b2 = fminf(b2, d);
            if (u == 3) b3 = fminf(b3, d);
        }
    }
    float best = fminf(fminf(b0, b1), fminf(b2, b3));
    float v = best;
    #pragma unroll
    for (int off = 32; off; off >>= 1) v += __shfl_down(v, off);
    __shared__ float red[4];
    int lane = threadIdx.x & 63, wid = threadIdx.x >> 6;
    if (lane == 0) red[wid] = v;
    __syncthreads();
    if (threadIdx.x == 0) {
        float s = (red[0] + red[1]) + (red[2] + red[3]);
        atomicAdd(out, s * (1.0f / (float)TOT));
    }
}

__global__ void zero_kernel(float* out) { out[0] = 0.0f; }

extern "C" void kernel_launch(void* const* d_in, const int* in_sizes, int n_in,
                              void* d_out, int out_size, void* d_ws, size_t ws_size,
                              hipStream_t stream) {
    const float* x = (const float*)d_in[0];
    const float* y = (const float*)d_in[1];
    float* out = (float*)d_out;

    // ws: Arec 2MB | Brec 2MB | colpart 4MB | rowpart 2MB
    size_t need = (size_t)10 << 20;
    if (ws_size >= need) {
        u16*   Arec    = (u16*)d_ws;
        u16*   Brec    = (u16*)((char*)d_ws + ((size_t)2 << 20));
        float* colpart = (float*)((char*)d_ws + ((size_t)4 << 20));
        float* rowpart = (float*)((char*)d_ws + ((size_t)8 << 20));
        hipLaunchKernelGGL(pack_mfma, dim3(TWOTOT / 256), dim3(256), 0, stream,
                           x, y, Arec, Brec, out);
        hipLaunchKernelGGL(chamfer_mfma, dim3(16 * 16 * JSEG), dim3(256), 0, stream,
                           Arec, Brec, colpart, rowpart);
        hipLaunchKernelGGL(chamfer_pass2, dim3(TOT / 256), dim3(256), 0, stream,
                           rowpart, colpart, out);
    } else {
        hipLaunchKernelGGL(zero_kernel, dim3(1), dim3(1), 0, stream, out);
        hipLaunchKernelGGL(chamfer_direct, dim3(512), dim3(256), 0, stream, x, y, out);
    }
}

// Round 19
// 42.865 us; speedup vs baseline: 1.3998x; 1.0104x over previous
//
#include <hip/hip_runtime.h>
#include <stdint.h>

#define BATCH 16
#define NPTS  4096
#define TOT   (BATCH * NPTS)     // 65536 points per tensor
#define TWOTOT (2 * TOT)
#define JSEG  8

typedef float f4 __attribute__((ext_vector_type(4)));
typedef float f32x4 __attribute__((ext_vector_type(4)));
typedef short bh8 __attribute__((ext_vector_type(8)));   // 8 bf16 = 4 VGPR
typedef uint32_t u32;
typedef unsigned short u16;

__device__ __forceinline__ u16 bfr(float f) {
    union { float f; u32 u; } v; v.f = f;
    u32 r = v.u + 0x7FFF + ((v.u >> 16) & 1);
    return (u16)(r >> 16);
}
__device__ __forceinline__ float bfback(u16 h) {
    union { u32 u; float f; } v; v.u = ((u32)h) << 16; return v.f;
}
#define BF16_ONE ((u16)0x3F80)

#define MIN3r(d, a, b, c) \
    asm("v_min3_f32 %0, %1, %2, %3" : "=v"(d) : "v"(a), "v"(b), "v"(c))

// pack: A-record per x-point, B-record per y-point (16 bf16 = 32B each).
//  A: [ahx,ahy,ahz, ahx,ahy,ahz, alx,aly, alz, x2h,x2l, 1,1, 0,0,0]   (A=-2x)
//  B: [yhx,yhy,yhz, ylx,yly,ylz, yhx,yhy, yhz, 1,1, y2h,y2l, 0,0,0]
// => sum_k A_k*B_k = Ah.Yh + Ah.Yl + Al.Yh + x2 + y2 == D[i,j]  (verified R14)
__global__ __launch_bounds__(256) void pack_mfma(const float* __restrict__ x,
                                                 const float* __restrict__ y,
                                                 u16* __restrict__ Arec,
                                                 u16* __restrict__ Brec,
                                                 float* __restrict__ out) {
    int idx = blockIdx.x * 256 + threadIdx.x;        // 0..2*TOT-1
    if (idx == 0) out[0] = 0.0f;

    bool isx = idx < TOT;
    int r = isx ? idx : (idx - TOT);
    const float* src = isx ? x : y;
    float a = src[r * 3 + 0];
    float b = src[r * 3 + 1];
    float c = src[r * 3 + 2];
    float s2 = fmaf(a, a, fmaf(b, b, c * c));
    u16 s2h = bfr(s2);
    u16 s2l = bfr(s2 - bfback(s2h));

    union { u16 h[16]; f4 v[2]; } rec;
    if (isx) {
        float ax = -2.0f * a, ay = -2.0f * b, az = -2.0f * c;
        u16 ahx = bfr(ax), ahy = bfr(ay), ahz = bfr(az);
        u16 alx = bfr(ax - bfback(ahx));
        u16 aly = bfr(ay - bfback(ahy));
        u16 alz = bfr(az - bfback(ahz));
        rec.h[0] = ahx;  rec.h[1] = ahy;  rec.h[2] = ahz;
        rec.h[3] = ahx;  rec.h[4] = ahy;  rec.h[5] = ahz;
        rec.h[6] = alx;  rec.h[7] = aly;
        rec.h[8] = alz;  rec.h[9] = s2h;  rec.h[10] = s2l;
        rec.h[11] = BF16_ONE; rec.h[12] = BF16_ONE;
        rec.h[13] = 0; rec.h[14] = 0; rec.h[15] = 0;
        f4* dst = (f4*)(Arec + (size_t)r * 16);
        dst[0] = rec.v[0]; dst[1] = rec.v[1];
    } else {
        u16 yhx = bfr(a), yhy = bfr(b), yhz = bfr(c);
        u16 ylx = bfr(a - bfback(yhx));
        u16 yly = bfr(b - bfback(yhy));
        u16 ylz = bfr(c - bfback(yhz));
        rec.h[0] = yhx;  rec.h[1] = yhy;  rec.h[2] = yhz;
        rec.h[3] = ylx;  rec.h[4] = yly;  rec.h[5] = ylz;
        rec.h[6] = yhx;  rec.h[7] = yhy;
        rec.h[8] = yhz;  rec.h[9] = BF16_ONE; rec.h[10] = BF16_ONE;
        rec.h[11] = s2h; rec.h[12] = s2l;
        rec.h[13] = 0; rec.h[14] = 0; rec.h[15] = 0;
        f4* dst = (f4*)(Brec + (size_t)r * 16);
        dst[0] = rec.v[0]; dst[1] = rec.v[1];
    }
}

// LDS frag read, immediate offset
#define DSRL(dst, base, imm) \
    asm volatile("ds_read_b128 %0, %1 offset:" imm : "=v"(dst) : "v"(base))

// counted lgkm wait (queue-simulated counts incl. interleaved ds_min)
#define WAITL(cnt, slot) do { \
    asm volatile("s_waitcnt lgkmcnt(" cnt ")" : "+v"(slot)); \
    __builtin_amdgcn_sched_barrier(0); \
} while (0)

// 8 MFMAs: 128 rows x 16 cols per B-frag read
#define MF8(BB) do { \
    p0 = __builtin_amdgcn_mfma_f32_16x16x32_bf16(af0, BB, zc, 0, 0, 0); \
    p1 = __builtin_amdgcn_mfma_f32_16x16x32_bf16(af1, BB, zc, 0, 0, 0); \
    p2 = __builtin_amdgcn_mfma_f32_16x16x32_bf16(af2, BB, zc, 0, 0, 0); \
    p3 = __builtin_amdgcn_mfma_f32_16x16x32_bf16(af3, BB, zc, 0, 0, 0); \
    p4 = __builtin_amdgcn_mfma_f32_16x16x32_bf16(af4, BB, zc, 0, 0, 0); \
    p5 = __builtin_amdgcn_mfma_f32_16x16x32_bf16(af5, BB, zc, 0, 0, 0); \
    p6 = __builtin_amdgcn_mfma_f32_16x16x32_bf16(af6, BB, zc, 0, 0, 0); \
    p7 = __builtin_amdgcn_mfma_f32_16x16x32_bf16(af7, BB, zc, 0, 0, 0); \
} while (0)

// per-tile epilogue: 32 rowmin folds + colmin tree over 32 values + 1 ds_min
#define EPI1() do { \
    ra0[0]=fminf(ra0[0],p0[0]); ra0[1]=fminf(ra0[1],p0[1]); ra0[2]=fminf(ra0[2],p0[2]); ra0[3]=fminf(ra0[3],p0[3]); \
    ra1[0]=fminf(ra1[0],p1[0]); ra1[1]=fminf(ra1[1],p1[1]); ra1[2]=fminf(ra1[2],p1[2]); ra1[3]=fminf(ra1[3],p1[3]); \
    ra2[0]=fminf(ra2[0],p2[0]); ra2[1]=fminf(ra2[1],p2[1]); ra2[2]=fminf(ra2[2],p2[2]); ra2[3]=fminf(ra2[3],p2[3]); \
    ra3[0]=fminf(ra3[0],p3[0]); ra3[1]=fminf(ra3[1],p3[1]); ra3[2]=fminf(ra3[2],p3[2]); ra3[3]=fminf(ra3[3],p3[3]); \
    ra4[0]=fminf(ra4[0],p4[0]); ra4[1]=fminf(ra4[1],p4[1]); ra4[2]=fminf(ra4[2],p4[2]); ra4[3]=fminf(ra4[3],p4[3]); \
    ra5[0]=fminf(ra5[0],p5[0]); ra5[1]=fminf(ra5[1],p5[1]); ra5[2]=fminf(ra5[2],p5[2]); ra5[3]=fminf(ra5[3],p5[3]); \
    ra6[0]=fminf(ra6[0],p6[0]); ra6[1]=fminf(ra6[1],p6[1]); ra6[2]=fminf(ra6[2],p6[2]); ra6[3]=fminf(ra6[3],p6[3]); \
    ra7[0]=fminf(ra7[0],p7[0]); ra7[1]=fminf(ra7[1],p7[1]); ra7[2]=fminf(ra7[2],p7[2]); ra7[3]=fminf(ra7[3],p7[3]); \
    float t0,t1,t2,t3,t4,t5,t6,t7,t8,t9,t10,u0,u1,u2,u3,cv; \
    MIN3r(t0, p0[0], p0[1], p0[2]); \
    MIN3r(t1, p0[3], p1[0], p1[1]); \
    MIN3r(t2, p1[2], p1[3], p2[0]); \
    MIN3r(t3, p2[1], p2[2], p2[3]); \
    MIN3r(t4, p3[0], p3[1], p3[2]); \
    MIN3r(t5, p3[3], p4[0], p4[1]); \
    MIN3r(t6, p4[2], p4[3], p5[0]); \
    MIN3r(t7, p5[1], p5[2], p5[3]); \
    MIN3r(t8, p6[0], p6[1], p6[2]); \
    MIN3r(t9, p6[3], p7[0], p7[1]); \
    MIN3r(t10, p7[2], p7[3], t0); \
    MIN3r(u0, t1, t2, t3); \
    MIN3r(u1, t4, t5, t6); \
    MIN3r(u2, t7, t8, t9); \
    MIN3r(u3, t10, u0, u1); \
    cv = fminf(u2, u3); \
    asm volatile("ds_min_f32 %0, %1" :: "v"(cma), "v"(cv)); \
    cma += 64; \
} while (0)

// Block = (batch, 512-row i-chunk, 512-col j-segment); 4 waves x 128 rows,
// A-stationary (8 frags); streams 32 16-col tiles, 4-slot rotating ds_read
// pipeline with queue-simulated counted lgkmcnt waits.
__global__ __launch_bounds__(256) void chamfer_mfma(const u16* __restrict__ Arec,
                                                    const u16* __restrict__ Brec,
                                                    float* __restrict__ colpart,
                                                    float* __restrict__ rowpart) {
    constexpr int QLEN = NPTS / JSEG;       // 512 cols
    __shared__ u16  Bst[QLEN * 16];         // 16 KB
    __shared__ float colmin[QLEN];          // 2 KB

    int bid  = blockIdx.x;                 // [b:16][ic:8][jseg:8]
    int b    = bid >> 6;
    int ic   = (bid >> 3) & 7;
    int jseg = bid & 7;
    int tid  = threadIdx.x;
    int wv   = tid >> 6, lane = tid & 63;
    int lg   = lane >> 4, lm = lane & 15;

    int i0 = ic * 512 + wv * 128;
    int j0 = jseg * QLEN;

    // stage B segment: 512 recs * 32B = 16KB, coalesced
    {
        const f4* src = (const f4*)(Brec + ((size_t)b * NPTS + j0) * 16);
        f4* dst = (f4*)Bst;
        int t4 = tid * 4;
        f4 v0 = src[t4 + 0], v1 = src[t4 + 1], v2 = src[t4 + 2], v3 = src[t4 + 3];
        dst[t4 + 0] = v0; dst[t4 + 1] = v1; dst[t4 + 2] = v2; dst[t4 + 3] = v3;
    }
    for (int i = tid; i < QLEN; i += 256) colmin[i] = 3.4e38f;

    // A frags (8 x 16 rows): lane = row lm, K-chunk lg*8; only lg<2 has data
    bh8 af0, af1, af2, af3, af4, af5, af6, af7;
    {
        bh8 z8 = {0, 0, 0, 0, 0, 0, 0, 0};
        const u16* ab = Arec + ((size_t)b * NPTS + i0 + lm) * 16 + lg * 8;
        af0 = (lg < 2) ? *(const bh8*)(ab + 0)    : z8;
        af1 = (lg < 2) ? *(const bh8*)(ab + 256)  : z8;
        af2 = (lg < 2) ? *(const bh8*)(ab + 512)  : z8;
        af3 = (lg < 2) ? *(const bh8*)(ab + 768)  : z8;
        af4 = (lg < 2) ? *(const bh8*)(ab + 1024) : z8;
        af5 = (lg < 2) ? *(const bh8*)(ab + 1280) : z8;
        af6 = (lg < 2) ? *(const bh8*)(ab + 1536) : z8;
        af7 = (lg < 2) ? *(const bh8*)(ab + 1792) : z8;
    }
    __syncthreads();                       // staging + colmin init complete

    u32 lofs = (u32)(uintptr_t)&Bst[0] + ((lg < 2) ? (u32)(lm * 32 + lg * 16) : 0u);
    u32 cma  = (u32)(uintptr_t)&colmin[0] + (u32)lm * 4;

    f32x4 zc = {0.f, 0.f, 0.f, 0.f};
    f32x4 big = {3.4e38f, 3.4e38f, 3.4e38f, 3.4e38f};
    f32x4 ra0 = big, ra1 = big, ra2 = big, ra3 = big;
    f32x4 ra4 = big, ra5 = big, ra6 = big, ra7 = big;
    f32x4 p0, p1, p2, p3, p4, p5, p6, p7;
    bh8 s0, s1, s2, s3;

    // prologue: tiles 0..3 (tile stride 512B)
    DSRL(s0, lofs, "0");    DSRL(s1, lofs, "512");
    DSRL(s2, lofs, "1024"); DSRL(s3, lofs, "1536");

    // tiles 0..3 (waits 3,4,5,6), prefetch tiles 4..7
    WAITL("3", s0); MF8(s0); DSRL(s0, lofs, "2048"); EPI1();
    WAITL("4", s1); MF8(s1); DSRL(s1, lofs, "2560"); EPI1();
    WAITL("5", s2); MF8(s2); DSRL(s2, lofs, "3072"); EPI1();
    WAITL("6", s3); MF8(s3); DSRL(s3, lofs, "3584"); EPI1();

    u32 lofs2 = lofs + 4096;               // prefetch base = tile 8
    #pragma unroll 1
    for (int k = 0; k < 6; ++k) {          // tiles 4..27, prefetch 8..31
        WAITL("7", s0); MF8(s0); DSRL(s0, lofs2, "0");    EPI1();
        WAITL("7", s1); MF8(s1); DSRL(s1, lofs2, "512");  EPI1();
        WAITL("7", s2); MF8(s2); DSRL(s2, lofs2, "1024"); EPI1();
        WAITL("7", s3); MF8(s3); DSRL(s3, lofs2, "1536"); EPI1();
        lofs2 += 2048;
    }
    // drain: tiles 28..31 (waits 7,6,5,4)
    WAITL("7", s0); MF8(s0); EPI1();
    WAITL("6", s1); MF8(s1); EPI1();
    WAITL("5", s2); MF8(s2); EPI1();
    WAITL("4", s3); MF8(s3); EPI1();

    // rowmin finalize: reduce across 16 col-lanes, write per-row values
    #define RRED(r) { r = fminf(r, __shfl_xor(r, 1)); r = fminf(r, __shfl_xor(r, 2)); \
                      r = fminf(r, __shfl_xor(r, 4)); r = fminf(r, __shfl_xor(r, 8)); }
    float* rp = rowpart + (size_t)jseg * TOT + (size_t)b * NPTS + i0 + lg * 4;
    #define RSTORE(pf, fi) do { \
        float a = pf[0], bq = pf[1], c = pf[2], d = pf[3]; \
        RRED(a) RRED(bq) RRED(c) RRED(d) \
        if (lm == 0) { rp[fi*16 + 0] = a; rp[fi*16 + 1] = bq; \
                       rp[fi*16 + 2] = c; rp[fi*16 + 3] = d; } \
    } while (0)
    RSTORE(ra0, 0); RSTORE(ra1, 1); RSTORE(ra2, 2); RSTORE(ra3, 3);
    RSTORE(ra4, 4); RSTORE(ra5, 5); RSTORE(ra6, 6); RSTORE(ra7, 7);

    __syncthreads();                       // all ds_min retired
    for (int j = tid; j < QLEN; j += 256)
        colpart[(size_t)ic * TOT + (size_t)b * NPTS + j0 + j] = colmin[j];
}

// pass2: fold row partials (8 jseg) + col partials (8 ic), mean both.
__global__ __launch_bounds__(256) void chamfer_pass2(const float* __restrict__ rowpart,
                                                     const float* __restrict__ colpart,
                                                     float* __restrict__ out) {
    int t = blockIdx.x * 256 + threadIdx.x;
    float mr = rowpart[t];
    #pragma unroll
    for (int s = 1; s < JSEG; ++s) mr = fminf(mr, rowpart[(size_t)s * TOT + t]);
    float mc = colpart[t];
    #pragma unroll
    for (int ic = 1; ic < 8; ++ic) mc = fminf(mc, colpart[(size_t)ic * TOT + t]);

    float s = mr + mc;
    #pragma unroll
    for (int off = 32; off; off >>= 1) s += __shfl_down(s, off);
    __shared__ float red[4];
    int lane = threadIdx.x & 63, wid = threadIdx.x >> 6;
    if (lane == 0) red[wid] = s;
    __syncthreads();
    if (threadIdx.x == 0) {
        float tot = (red[0] + red[1]) + (red[2] + red[3]);
        atomicAdd(out, tot * (1.0f / (float)TOT));
    }
}

// ---------------- fallback (no workspace): direct form ----------------
__global__ __launch_bounds__(256) void chamfer_direct(const float* __restrict__ x,
                                                      const float* __restrict__ y,
                                                      float* __restrict__ out) {
    int blk = blockIdx.x;
    int dir = blk >> 8;
    int t = blk & 255;
    int b = t >> 4;
    int chunk = t & 15;
    const float* __restrict__ P = (dir ? y : x) + (b * NPTS + chunk * 256) * 3;
    const float* __restrict__ Q = (dir ? x : y) + b * NPTS * 3;
    float px = P[threadIdx.x * 3 + 0];
    float py = P[threadIdx.x * 3 + 1];
    float pz = P[threadIdx.x * 3 + 2];
    float b0 = 3.4e38f, b1 = 3.4e38f, b2 = 3.4e38f, b3 = 3.4e38f;
    for (int j = 0; j < NPTS; j += 4) {
        #pragma unroll
        for (int u = 0; u < 4; ++u) {
            float dx = px - Q[(j + u) * 3 + 0];
            float dy = py - Q[(j + u) * 3 + 1];
            float dz = pz - Q[(j + u) * 3 + 2];
            float d = fmaf(dx, dx, fmaf(dy, dy, dz * dz));
            if (u == 0) b0 = fminf(b0, d);
            if (u == 1) b1 = fminf(b1, d);
            if (u == 2) b2 = fminf(b2, d);
            if (u == 3) b3 = fminf(b3, d);
        }
    }
    float best = fminf(fminf(b0, b1), fminf(b2, b3));
    float v = best;
    #pragma unroll
    for (int off = 32; off; off >>= 1) v += __shfl_down(v, off);
    __shared__ float red[4];
    int lane = threadIdx.x & 63, wid = threadIdx.x >> 6;
    if (lane == 0) red[wid] = v;
    __syncthreads();
    if (threadIdx.x == 0) {
        float s = (red[0] + red[1]) + (red[2] + red[3]);
        atomicAdd(out, s * (1.0f / (float)TOT));
    }
}

__global__ void zero_kernel(float* out) { out[0] = 0.0f; }

extern "C" void kernel_launch(void* const* d_in, const int* in_sizes, int n_in,
                              void* d_out, int out_size, void* d_ws, size_t ws_size,
                              hipStream_t stream) {
    const float* x = (const float*)d_in[0];
    const float* y = (const float*)d_in[1];
    float* out = (float*)d_out;

    // ws: Arec 2MB | Brec 2MB | colpart 2MB | rowpart 2MB
    size_t need = (size_t)8 << 20;
    if (ws_size >= need) {
        u16*   Arec    = (u16*)d_ws;
        u16*   Brec    = (u16*)((char*)d_ws + ((size_t)2 << 20));
        float* colpart = (float*)((char*)d_ws + ((size_t)4 << 20));
        float* rowpart = (float*)((char*)d_ws + ((size_t)6 << 20));
        hipLaunchKernelGGL(pack_mfma, dim3(TWOTOT / 256), dim3(256), 0, stream,
                           x, y, Arec, Brec, out);
        hipLaunchKernelGGL(chamfer_mfma, dim3(16 * 8 * JSEG), dim3(256), 0, stream,
                           Arec, Brec, colpart, rowpart);
        hipLaunchKernelGGL(chamfer_pass2, dim3(TOT / 256), dim3(256), 0, stream,
                           rowpart, colpart, out);
    } else {
        hipLaunchKernelGGL(zero_kernel, dim3(1), dim3(1), 0, stream, out);
        hipLaunchKernelGGL(chamfer_direct, dim3(512), dim3(256), 0, stream, x, y, out);
    }
}

// Round 20
// 39.084 us; speedup vs baseline: 1.5352x; 1.0967x over previous
//
#include <hip/hip_runtime.h>
#include <stdint.h>

#define BATCH 16
#define NPTS  4096
#define TOT   (BATCH * NPTS)     // 65536 points per tensor
#define JSEG  8

typedef float f4 __attribute__((ext_vector_type(4)));
typedef float f32x4 __attribute__((ext_vector_type(4)));
typedef short bh8 __attribute__((ext_vector_type(8)));   // 8 bf16 = 4 VGPR
typedef uint32_t u32;
typedef unsigned short u16;

__device__ __forceinline__ u16 bfr(float f) {
    union { float f; u32 u; } v; v.f = f;
    u32 r = v.u + 0x7FFF + ((v.u >> 16) & 1);
    return (u16)(r >> 16);
}
__device__ __forceinline__ float bfback(u16 h) {
    union { u32 u; float f; } v; v.u = ((u32)h) << 16; return v.f;
}
#define BF16_ONE ((u16)0x3F80)

#define MIN3r(d, a, b, c) \
    asm("v_min3_f32 %0, %1, %2, %3" : "=v"(d) : "v"(a), "v"(b), "v"(c))

// Record layout (verified R14):
//  A: [ahx,ahy,ahz, ahx,ahy,ahz, alx,aly | alz, x2h,x2l, 1,1, 0,0,0]   (A=-2x)
//  B: [yhx,yhy,yhz, ylx,yly,ylz, yhx,yhy | yhz, 1,1, y2h,y2l, 0,0,0]
// => sum_k A_k*B_k = Ah.Yh + Ah.Yl + Al.Yh + x2 + y2 == D[i,j]

// build A-record halves for one x-point (in registers)
__device__ __forceinline__ void build_arec(float a, float b, float c,
                                           bh8* h0, bh8* h1) {
    float s2 = fmaf(a, a, fmaf(b, b, c * c));
    u16 s2h = bfr(s2);
    u16 s2l = bfr(s2 - bfback(s2h));
    float ax = -2.0f * a, ay = -2.0f * b, az = -2.0f * c;
    u16 ahx = bfr(ax), ahy = bfr(ay), ahz = bfr(az);
    u16 alx = bfr(ax - bfback(ahx));
    u16 aly = bfr(ay - bfback(ahy));
    u16 alz = bfr(az - bfback(ahz));
    union { u16 h[8]; bh8 v; } r0, r1;
    r0.h[0] = ahx; r0.h[1] = ahy; r0.h[2] = ahz;
    r0.h[3] = ahx; r0.h[4] = ahy; r0.h[5] = ahz;
    r0.h[6] = alx; r0.h[7] = aly;
    r1.h[0] = alz; r1.h[1] = s2h; r1.h[2] = s2l;
    r1.h[3] = BF16_ONE; r1.h[4] = BF16_ONE;
    r1.h[5] = 0; r1.h[6] = 0; r1.h[7] = 0;
    *h0 = r0.v; *h1 = r1.v;
}

// build B-record (16 u16 = two f4) for one y-point
__device__ __forceinline__ void build_brec(float a, float b, float c,
                                           f4* v0, f4* v1) {
    float s2 = fmaf(a, a, fmaf(b, b, c * c));
    u16 s2h = bfr(s2);
    u16 s2l = bfr(s2 - bfback(s2h));
    u16 yhx = bfr(a), yhy = bfr(b), yhz = bfr(c);
    u16 ylx = bfr(a - bfback(yhx));
    u16 yly = bfr(b - bfback(yhy));
    u16 ylz = bfr(c - bfback(yhz));
    union { u16 h[16]; f4 v[2]; } rec;
    rec.h[0] = yhx;  rec.h[1] = yhy;  rec.h[2] = yhz;
    rec.h[3] = ylx;  rec.h[4] = yly;  rec.h[5] = ylz;
    rec.h[6] = yhx;  rec.h[7] = yhy;
    rec.h[8] = yhz;  rec.h[9] = BF16_ONE; rec.h[10] = BF16_ONE;
    rec.h[11] = s2h; rec.h[12] = s2l;
    rec.h[13] = 0; rec.h[14] = 0; rec.h[15] = 0;
    *v0 = rec.v[0]; *v1 = rec.v[1];
}

// LDS frag read, immediate offset
#define DSRL(dst, base, imm) \
    asm volatile("ds_read_b128 %0, %1 offset:" imm : "=v"(dst) : "v"(base))

// counted lgkm wait (queue-simulated counts incl. interleaved ds_min)
#define WAITL(cnt, slot) do { \
    asm volatile("s_waitcnt lgkmcnt(" cnt ")" : "+v"(slot)); \
    __builtin_amdgcn_sched_barrier(0); \
} while (0)

// 8 MFMAs: 128 rows x 16 cols per B-frag read
#define MF8(BB) do { \
    p0 = __builtin_amdgcn_mfma_f32_16x16x32_bf16(af0, BB, zc, 0, 0, 0); \
    p1 = __builtin_amdgcn_mfma_f32_16x16x32_bf16(af1, BB, zc, 0, 0, 0); \
    p2 = __builtin_amdgcn_mfma_f32_16x16x32_bf16(af2, BB, zc, 0, 0, 0); \
    p3 = __builtin_amdgcn_mfma_f32_16x16x32_bf16(af3, BB, zc, 0, 0, 0); \
    p4 = __builtin_amdgcn_mfma_f32_16x16x32_bf16(af4, BB, zc, 0, 0, 0); \
    p5 = __builtin_amdgcn_mfma_f32_16x16x32_bf16(af5, BB, zc, 0, 0, 0); \
    p6 = __builtin_amdgcn_mfma_f32_16x16x32_bf16(af6, BB, zc, 0, 0, 0); \
    p7 = __builtin_amdgcn_mfma_f32_16x16x32_bf16(af7, BB, zc, 0, 0, 0); \
} while (0)

// per-tile epilogue: 32 rowmin folds + colmin tree over 32 values + 1 ds_min
#define EPI1() do { \
    ra0[0]=fminf(ra0[0],p0[0]); ra0[1]=fminf(ra0[1],p0[1]); ra0[2]=fminf(ra0[2],p0[2]); ra0[3]=fminf(ra0[3],p0[3]); \
    ra1[0]=fminf(ra1[0],p1[0]); ra1[1]=fminf(ra1[1],p1[1]); ra1[2]=fminf(ra1[2],p1[2]); ra1[3]=fminf(ra1[3],p1[3]); \
    ra2[0]=fminf(ra2[0],p2[0]); ra2[1]=fminf(ra2[1],p2[1]); ra2[2]=fminf(ra2[2],p2[2]); ra2[3]=fminf(ra2[3],p2[3]); \
    ra3[0]=fminf(ra3[0],p3[0]); ra3[1]=fminf(ra3[1],p3[1]); ra3[2]=fminf(ra3[2],p3[2]); ra3[3]=fminf(ra3[3],p3[3]); \
    ra4[0]=fminf(ra4[0],p4[0]); ra4[1]=fminf(ra4[1],p4[1]); ra4[2]=fminf(ra4[2],p4[2]); ra4[3]=fminf(ra4[3],p4[3]); \
    ra5[0]=fminf(ra5[0],p5[0]); ra5[1]=fminf(ra5[1],p5[1]); ra5[2]=fminf(ra5[2],p5[2]); ra5[3]=fminf(ra5[3],p5[3]); \
    ra6[0]=fminf(ra6[0],p6[0]); ra6[1]=fminf(ra6[1],p6[1]); ra6[2]=fminf(ra6[2],p6[2]); ra6[3]=fminf(ra6[3],p6[3]); \
    ra7[0]=fminf(ra7[0],p7[0]); ra7[1]=fminf(ra7[1],p7[1]); ra7[2]=fminf(ra7[2],p7[2]); ra7[3]=fminf(ra7[3],p7[3]); \
    float t0,t1,t2,t3,t4,t5,t6,t7,t8,t9,t10,u0,u1,u2,u3,cv; \
    MIN3r(t0, p0[0], p0[1], p0[2]); \
    MIN3r(t1, p0[3], p1[0], p1[1]); \
    MIN3r(t2, p1[2], p1[3], p2[0]); \
    MIN3r(t3, p2[1], p2[2], p2[3]); \
    MIN3r(t4, p3[0], p3[1], p3[2]); \
    MIN3r(t5, p3[3], p4[0], p4[1]); \
    MIN3r(t6, p4[2], p4[3], p5[0]); \
    MIN3r(t7, p5[1], p5[2], p5[3]); \
    MIN3r(t8, p6[0], p6[1], p6[2]); \
    MIN3r(t9, p6[3], p7[0], p7[1]); \
    MIN3r(t10, p7[2], p7[3], t0); \
    MIN3r(u0, t1, t2, t3); \
    MIN3r(u1, t4, t5, t6); \
    MIN3r(u2, t7, t8, t9); \
    MIN3r(u3, t10, u0, u1); \
    cv = fminf(u2, u3); \
    asm volatile("ds_min_f32 %0, %1" :: "v"(cma), "v"(cv)); \
    cma += 64; \
} while (0)

// Fused: block = (batch, 512-row i-chunk, 512-col j-segment); builds its own
// A-frags (registers) and B-records (LDS) from raw x/y - no pack kernel.
// Loop identical to R19 (verified): 4-slot rotating ds_read pipeline,
// queue-simulated counted lgkmcnt waits.
__global__ __launch_bounds__(256) void chamfer_mfma(const float* __restrict__ x,
                                                    const float* __restrict__ y,
                                                    float* __restrict__ colpart,
                                                    float* __restrict__ rowpart,
                                                    float* __restrict__ out) {
    constexpr int QLEN = NPTS / JSEG;       // 512 cols
    __shared__ u16  Bst[QLEN * 16];         // 16 KB
    __shared__ float colmin[QLEN];          // 2 KB

    int bid  = blockIdx.x;                 // [b:16][ic:8][jseg:8]
    int b    = bid >> 6;
    int ic   = (bid >> 3) & 7;
    int jseg = bid & 7;
    int tid  = threadIdx.x;
    int wv   = tid >> 6, lane = tid & 63;
    int lg   = lane >> 4, lm = lane & 15;

    if (bid == 0 && tid == 0) out[0] = 0.0f;   // stream-ordered before pass2

    int i0 = ic * 512 + wv * 128;
    int j0 = jseg * QLEN;

    // stage B segment: 2 records per thread, built from raw y
    {
        const float* ysrc = y + ((size_t)b * NPTS + j0) * 3;
        f4* dst = (f4*)Bst;
        #pragma unroll
        for (int r = 0; r < 2; ++r) {
            int rec = tid * 2 + r;
            float a = ysrc[rec * 3 + 0];
            float bb = ysrc[rec * 3 + 1];
            float c = ysrc[rec * 3 + 2];
            f4 v0, v1;
            build_brec(a, bb, c, &v0, &v1);
            dst[rec * 2 + 0] = v0;
            dst[rec * 2 + 1] = v1;
        }
    }
    for (int i = tid; i < QLEN; i += 256) colmin[i] = 3.4e38f;

    // A frags (8 x 16 rows) built in registers from raw x. Thread (lm,lg)
    // owns row i0+lm+f*16; af = half lg of that row's record (lg>=2 -> 0).
    bh8 af0, af1, af2, af3, af4, af5, af6, af7;
    {
        bh8 z8 = {0, 0, 0, 0, 0, 0, 0, 0};
        const float* xsrc = x + ((size_t)b * NPTS + i0 + lm) * 3;
        #define BUILD_AF(af, f) do { \
            float a = xsrc[f * 48 + 0]; \
            float bb = xsrc[f * 48 + 1]; \
            float c = xsrc[f * 48 + 2]; \
            bh8 h0, h1; \
            build_arec(a, bb, c, &h0, &h1); \
            af = (lg == 0) ? h0 : ((lg == 1) ? h1 : z8); \
        } while (0)
        BUILD_AF(af0, 0); BUILD_AF(af1, 1); BUILD_AF(af2, 2); BUILD_AF(af3, 3);
        BUILD_AF(af4, 4); BUILD_AF(af5, 5); BUILD_AF(af6, 6); BUILD_AF(af7, 7);
        #undef BUILD_AF
    }
    __syncthreads();                       // staging + colmin init complete

    u32 lofs = (u32)(uintptr_t)&Bst[0] + ((lg < 2) ? (u32)(lm * 32 + lg * 16) : 0u);
    u32 cma  = (u32)(uintptr_t)&colmin[0] + (u32)lm * 4;

    f32x4 zc = {0.f, 0.f, 0.f, 0.f};
    f32x4 big = {3.4e38f, 3.4e38f, 3.4e38f, 3.4e38f};
    f32x4 ra0 = big, ra1 = big, ra2 = big, ra3 = big;
    f32x4 ra4 = big, ra5 = big, ra6 = big, ra7 = big;
    f32x4 p0, p1, p2, p3, p4, p5, p6, p7;
    bh8 s0, s1, s2, s3;

    // prologue: tiles 0..3 (tile stride 512B)
    DSRL(s0, lofs, "0");    DSRL(s1, lofs, "512");
    DSRL(s2, lofs, "1024"); DSRL(s3, lofs, "1536");

    // tiles 0..3 (waits 3,4,5,6), prefetch tiles 4..7
    WAITL("3", s0); MF8(s0); DSRL(s0, lofs, "2048"); EPI1();
    WAITL("4", s1); MF8(s1); DSRL(s1, lofs, "2560"); EPI1();
    WAITL("5", s2); MF8(s2); DSRL(s2, lofs, "3072"); EPI1();
    WAITL("6", s3); MF8(s3); DSRL(s3, lofs, "3584"); EPI1();

    u32 lofs2 = lofs + 4096;               // prefetch base = tile 8
    #pragma unroll 1
    for (int k = 0; k < 6; ++k) {          // tiles 4..27, prefetch 8..31
        WAITL("7", s0); MF8(s0); DSRL(s0, lofs2, "0");    EPI1();
        WAITL("7", s1); MF8(s1); DSRL(s1, lofs2, "512");  EPI1();
        WAITL("7", s2); MF8(s2); DSRL(s2, lofs2, "1024"); EPI1();
        WAITL("7", s3); MF8(s3); DSRL(s3, lofs2, "1536"); EPI1();
        lofs2 += 2048;
    }
    // drain: tiles 28..31 (waits 7,6,5,4)
    WAITL("7", s0); MF8(s0); EPI1();
    WAITL("6", s1); MF8(s1); EPI1();
    WAITL("5", s2); MF8(s2); EPI1();
    WAITL("4", s3); MF8(s3); EPI1();

    // rowmin finalize: reduce across 16 col-lanes, write per-row values
    #define RRED(r) { r = fminf(r, __shfl_xor(r, 1)); r = fminf(r, __shfl_xor(r, 2)); \
                      r = fminf(r, __shfl_xor(r, 4)); r = fminf(r, __shfl_xor(r, 8)); }
    float* rp = rowpart + (size_t)jseg * TOT + (size_t)b * NPTS + i0 + lg * 4;
    #define RSTORE(pf, fi) do { \
        float a = pf[0], bq = pf[1], c = pf[2], d = pf[3]; \
        RRED(a) RRED(bq) RRED(c) RRED(d) \
        if (lm == 0) { rp[fi*16 + 0] = a; rp[fi*16 + 1] = bq; \
                       rp[fi*16 + 2] = c; rp[fi*16 + 3] = d; } \
    } while (0)
    RSTORE(ra0, 0); RSTORE(ra1, 1); RSTORE(ra2, 2); RSTORE(ra3, 3);
    RSTORE(ra4, 4); RSTORE(ra5, 5); RSTORE(ra6, 6); RSTORE(ra7, 7);

    __syncthreads();                       // all ds_min retired
    for (int j = tid; j < QLEN; j += 256)
        colpart[(size_t)ic * TOT + (size_t)b * NPTS + j0 + j] = colmin[j];
}

// pass2: fold row partials (8 jseg) + col partials (8 ic), mean both.
__global__ __launch_bounds__(256) void chamfer_pass2(const float* __restrict__ rowpart,
                                                     const float* __restrict__ colpart,
                                                     float* __restrict__ out) {
    int t = blockIdx.x * 256 + threadIdx.x;
    float mr = rowpart[t];
    #pragma unroll
    for (int s = 1; s < JSEG; ++s) mr = fminf(mr, rowpart[(size_t)s * TOT + t]);
    float mc = colpart[t];
    #pragma unroll
    for (int ic = 1; ic < 8; ++ic) mc = fminf(mc, colpart[(size_t)ic * TOT + t]);

    float s = mr + mc;
    #pragma unroll
    for (int off = 32; off; off >>= 1) s += __shfl_down(s, off);
    __shared__ float red[4];
    int lane = threadIdx.x & 63, wid = threadIdx.x >> 6;
    if (lane == 0) red[wid] = s;
    __syncthreads();
    if (threadIdx.x == 0) {
        float tot = (red[0] + red[1]) + (red[2] + red[3]);
        atomicAdd(out, tot * (1.0f / (float)TOT));
    }
}

// ---------------- fallback (no workspace): direct form ----------------
__global__ __launch_bounds__(256) void chamfer_direct(const float* __restrict__ x,
                                                      const float* __restrict__ y,
                                                      float* __restrict__ out) {
    int blk = blockIdx.x;
    int dir = blk >> 8;
    int t = blk & 255;
    int b = t >> 4;
    int chunk = t & 15;
    const float* __restrict__ P = (dir ? y : x) + (b * NPTS + chunk * 256) * 3;
    const float* __restrict__ Q = (dir ? x : y) + b * NPTS * 3;
    float px = P[threadIdx.x * 3 + 0];
    float py = P[threadIdx.x * 3 + 1];
    float pz = P[threadIdx.x * 3 + 2];
    float b0 = 3.4e38f, b1 = 3.4e38f, b2 = 3.4e38f, b3 = 3.4e38f;
    for (int j = 0; j < NPTS; j += 4) {
        #pragma unroll
        for (int u = 0; u < 4; ++u) {
            float dx = px - Q[(j + u) * 3 + 0];
            float dy = py - Q[(j + u) * 3 + 1];
            float dz = pz - Q[(j + u) * 3 + 2];
            float d = fmaf(dx, dx, fmaf(dy, dy, dz * dz));
            if (u == 0) b0 = fminf(b0, d);
            if (u == 1) b1 = fminf(b1, d);
            if (u == 2) b2 = fminf(b2, d);
            if (u == 3) b3 = fminf(b3, d);
        }
    }
    float best = fminf(fminf(b0, b1), fminf(b2, b3));
    float v = best;
    #pragma unroll
    for (int off = 32; off; off >>= 1) v += __shfl_down(v, off);
    __shared__ float red[4];
    int lane = threadIdx.x & 63, wid = threadIdx.x >> 6;
    if (lane == 0) red[wid] = v;
    __syncthreads();
    if (threadIdx.x == 0) {
        float s = (red[0] + red[1]) + (red[2] + red[3]);
        atomicAdd(out, s * (1.0f / (float)TOT));
    }
}

__global__ void zero_kernel(float* out) { out[0] = 0.0f; }

extern "C" void kernel_launch(void* const* d_in, const int* in_sizes, int n_in,
                              void* d_out, int out_size, void* d_ws, size_t ws_size,
                              hipStream_t stream) {
    const float* x = (const float*)d_in[0];
    const float* y = (const float*)d_in[1];
    float* out = (float*)d_out;

    // ws: colpart 2MB | rowpart 2MB
    size_t need = (size_t)4 << 20;
    if (ws_size >= need) {
        float* colpart = (float*)d_ws;
        float* rowpart = (float*)((char*)d_ws + ((size_t)2 << 20));
        hipLaunchKernelGGL(chamfer_mfma, dim3(16 * 8 * JSEG), dim3(256), 0, stream,
                           x, y, colpart, rowpart, out);
        hipLaunchKernelGGL(chamfer_pass2, dim3(TOT / 256), dim3(256), 0, stream,
                           rowpart, colpart, out);
    } else {
        hipLaunchKernelGGL(zero_kernel, dim3(1), dim3(1), 0, stream, out);
        hipLaunchKernelGGL(chamfer_direct, dim3(512), dim3(256), 0, stream, x, y, out);
    }
}